// Round 2
// baseline (2396.681 us; speedup 1.0000x reference)
//
#include <hip/hip_runtime.h>
#include <math.h>

#define DIMX 1024
#define QKD  128
#define HIDD 2048
#define BATCH 4
#define SEQ  2048

__device__ __forceinline__ float siluf(float v) { return v / (1.f + expf(-v)); }

// -------------------- LayerNorm --------------------
__global__ __launch_bounds__(256) void ln_kernel(const float* __restrict__ x,
                                                 const float* __restrict__ scale,
                                                 const float* __restrict__ bias,
                                                 float* __restrict__ xn) {
    const int row = blockIdx.x;
    const float4 v = reinterpret_cast<const float4*>(x + (size_t)row * DIMX)[threadIdx.x];
    float s  = v.x + v.y + v.z + v.w;
    float ss = v.x * v.x + v.y * v.y + v.z * v.z + v.w * v.w;
    #pragma unroll
    for (int off = 32; off; off >>= 1) {
        s  += __shfl_down(s, off);
        ss += __shfl_down(ss, off);
    }
    __shared__ float ls[4], lss[4];
    const int wid = threadIdx.x >> 6, lane = threadIdx.x & 63;
    if (lane == 0) { ls[wid] = s; lss[wid] = ss; }
    __syncthreads();
    if (threadIdx.x == 0) {
        float a = ls[0] + ls[1] + ls[2] + ls[3];
        float b = lss[0] + lss[1] + lss[2] + lss[3];
        float mu  = a / DIMX;
        float var = b / DIMX - mu * mu;
        ls[0]  = mu;
        lss[0] = rsqrtf(var + 1e-5f);
    }
    __syncthreads();
    const float mu = ls[0], rs = lss[0];
    const float4 sc = reinterpret_cast<const float4*>(scale)[threadIdx.x];
    const float4 bi = reinterpret_cast<const float4*>(bias)[threadIdx.x];
    float4 o;
    o.x = (v.x - mu) * rs * sc.x + bi.x;
    o.y = (v.y - mu) * rs * sc.y + bi.y;
    o.z = (v.z - mu) * rs * sc.z + bi.z;
    o.w = (v.w - mu) * rs * sc.w + bi.w;
    reinterpret_cast<float4*>(xn + (size_t)row * DIMX)[threadIdx.x] = o;
}

// -------------------- Generic fp32 tiled GEMM, 64x64x16, 256 threads --------------------
// EPI: 0 = silu(acc+E0) -> C
//      1 = s=silu(acc+E0); C=s*E1[c]+E2[c]; O2=s*E1[QKD+c]+E2[QKD+c]   (q,k GEMM)
//      2 = relu(acc*scale)^2 -> C
//      3 = acc * C[row,col] -> C   (gate read in place, then overwritten by y)
//      4 = acc + E0 -> C
// BTRANS: B is [N x K] row-major, use B^T
template<int EPI, bool BTRANS>
__global__ __launch_bounds__(256) void gemm64(
    const float* __restrict__ A, int lda, long long sA,
    const float* __restrict__ B, int ldb, long long sB,
    float* __restrict__ C, int ldc, long long sC,
    const float* __restrict__ E0,
    const float* __restrict__ E1,
    const float* __restrict__ E2,
    float* __restrict__ O2,
    int M, int N, int K, float scale) {
    __shared__ float As[16][64];
    __shared__ float Bs[16][64];

    const int z = blockIdx.z;
    A += (size_t)sA * z;
    B += (size_t)sB * z;
    C += (size_t)sC * z;

    const int tid = threadIdx.x;
    const int tx = tid & 15, ty = tid >> 4;
    const int bm = blockIdx.y * 64, bn = blockIdx.x * 64;

    float acc[4][4] = {};

    const int arow = tid >> 2, ac4 = tid & 3;
    const float* Ap = A + (size_t)(bm + arow) * lda + ac4 * 4;
    const float* Bp;
    if (!BTRANS) {
        Bp = B + (size_t)(tid >> 4) * ldb + bn + (tid & 15) * 4;
    } else {
        Bp = B + (size_t)(bn + (tid >> 2)) * ldb + (tid & 3) * 4;
    }

    for (int k0 = 0; k0 < K; k0 += 16) {
        const float4 av = *reinterpret_cast<const float4*>(Ap + k0);
        As[ac4 * 4 + 0][arow] = av.x;
        As[ac4 * 4 + 1][arow] = av.y;
        As[ac4 * 4 + 2][arow] = av.z;
        As[ac4 * 4 + 3][arow] = av.w;
        if (!BTRANS) {
            const float4 bv = *reinterpret_cast<const float4*>(Bp + (size_t)k0 * ldb);
            *reinterpret_cast<float4*>(&Bs[tid >> 4][(tid & 15) * 4]) = bv;
        } else {
            const float4 bv = *reinterpret_cast<const float4*>(Bp + k0);
            const int j = tid >> 2, c4 = tid & 3;
            Bs[c4 * 4 + 0][j] = bv.x;
            Bs[c4 * 4 + 1][j] = bv.y;
            Bs[c4 * 4 + 2][j] = bv.z;
            Bs[c4 * 4 + 3][j] = bv.w;
        }
        __syncthreads();
        #pragma unroll
        for (int kk = 0; kk < 16; ++kk) {
            const float4 a = *reinterpret_cast<const float4*>(&As[kk][ty * 4]);
            const float4 b = *reinterpret_cast<const float4*>(&Bs[kk][tx * 4]);
            const float aa[4] = {a.x, a.y, a.z, a.w};
            const float bb[4] = {b.x, b.y, b.z, b.w};
            #pragma unroll
            for (int i = 0; i < 4; ++i)
                #pragma unroll
                for (int j = 0; j < 4; ++j)
                    acc[i][j] = fmaf(aa[i], bb[j], acc[i][j]);
        }
        __syncthreads();
    }

    #pragma unroll
    for (int i = 0; i < 4; ++i) {
        const int row = bm + ty * 4 + i;
        const int col0 = bn + tx * 4;
        if constexpr (EPI == 1) {
            float rq[4], rk[4];
            #pragma unroll
            for (int j = 0; j < 4; ++j) {
                const float s = siluf(acc[i][j] + E0[col0 + j]);
                rq[j] = s * E1[col0 + j] + E2[col0 + j];
                rk[j] = s * E1[QKD + col0 + j] + E2[QKD + col0 + j];
            }
            *reinterpret_cast<float4*>(&C[(size_t)row * ldc + col0]) = make_float4(rq[0], rq[1], rq[2], rq[3]);
            *reinterpret_cast<float4*>(&O2[(size_t)row * ldc + col0]) = make_float4(rk[0], rk[1], rk[2], rk[3]);
        } else {
            float r[4];
            #pragma unroll
            for (int j = 0; j < 4; ++j) {
                float v = acc[i][j];
                const int col = col0 + j;
                if constexpr (EPI == 0) { v += E0[col]; v = siluf(v); }
                else if constexpr (EPI == 2) { v *= scale; v = v > 0.f ? v * v : 0.f; }
                else if constexpr (EPI == 3) { v *= C[(size_t)row * ldc + col]; }
                else if constexpr (EPI == 4) { v += E0[col]; }
                r[j] = v;
            }
            *reinterpret_cast<float4*>(&C[(size_t)row * ldc + col0]) = make_float4(r[0], r[1], r[2], r[3]);
        }
    }
}

extern "C" void kernel_launch(void* const* d_in, const int* in_sizes, int n_in,
                              void* d_out, int out_size, void* d_ws, size_t ws_size,
                              hipStream_t stream) {
    const float* x        = (const float*)d_in[0];
    const float* ln_scale = (const float*)d_in[1];
    const float* ln_bias  = (const float*)d_in[2];
    const float* W_hidden = (const float*)d_in[3];
    const float* b_hidden = (const float*)d_in[4];
    const float* W_qk     = (const float*)d_in[5];
    const float* b_qk     = (const float*)d_in[6];
    const float* os_w     = (const float*)d_in[7];
    const float* os_b     = (const float*)d_in[8];
    const float* W_out    = (const float*)d_in[9];
    const float* b_out    = (const float*)d_in[10];
    float* out = (float*)d_out;
    float* ws  = (float*)d_ws;

    // scratch per batch (floats): hid 2048*4096 + qb 2048*128 + kb 2048*128 + attn 2048*2048
    const size_t perB = 13107200ull;           // = 50 MiB as bytes*4
    int NB = (ws_size >= 4 * perB * sizeof(float)) ? 4
           : (ws_size >= 2 * perB * sizeof(float)) ? 2 : 1;

    for (int b0 = 0; b0 < BATCH; b0 += NB) {
        const int nb = NB;
        const int ROWS = nb * SEQ;
        const float* xb = x   + (size_t)b0 * SEQ * DIMX;
        float* xn   = out + (size_t)b0 * SEQ * DIMX;   // d_out doubles as xn scratch
        float* outb = out + (size_t)b0 * SEQ * DIMX;
        float* hid  = ws;                                          // [ROWS][4096]  v | gate
        float* qb   = hid + (size_t)nb * SEQ * (2 * HIDD);
        float* kb   = qb  + (size_t)nb * SEQ * QKD;
        float* attn = kb  + (size_t)nb * SEQ * QKD;                // [nb][2048][2048]

        // 1) LayerNorm (xn into d_out rows)
        ln_kernel<<<ROWS, 256, 0, stream>>>(xb, ln_scale, ln_bias, xn);

        // 2) hid = silu(xn @ W_hidden + b_hidden)   [ROWS x 4096]
        gemm64<0, false><<<dim3(2 * HIDD / 64, ROWS / 64, 1), 256, 0, stream>>>(
            xn, DIMX, 0, W_hidden, 2 * HIDD, 0, hid, 2 * HIDD, 0,
            b_hidden, nullptr, nullptr, nullptr, ROWS, 2 * HIDD, DIMX, 0.f);

        // 3) q,k from silu(xn @ W_qk + b_qk)   [ROWS x 128]
        gemm64<1, false><<<dim3(QKD / 64, ROWS / 64, 1), 256, 0, stream>>>(
            xn, DIMX, 0, W_qk, QKD, 0, qb, QKD, 0,
            b_qk, os_w, os_b, kb, ROWS, QKD, DIMX, 0.f);

        // 4) attn = relu(q @ k^T / n)^2   per batch
        gemm64<2, true><<<dim3(SEQ / 64, SEQ / 64, nb), 256, 0, stream>>>(
            qb, QKD, (long long)SEQ * QKD, kb, QKD, (long long)SEQ * QKD,
            attn, SEQ, (long long)SEQ * SEQ,
            nullptr, nullptr, nullptr, nullptr, SEQ, SEQ, QKD, 1.0f / SEQ);

        // 5) y = (attn @ v) * gate, y written in place over gate (cols HIDD..)
        gemm64<3, false><<<dim3(HIDD / 64, SEQ / 64, nb), 256, 0, stream>>>(
            attn, SEQ, (long long)SEQ * SEQ, hid, 2 * HIDD, (long long)SEQ * 2 * HIDD,
            hid + HIDD, 2 * HIDD, (long long)SEQ * 2 * HIDD,
            nullptr, nullptr, nullptr, nullptr, SEQ, HIDD, SEQ, 0.f);

        // 6) out = y @ W_out + b_out   [ROWS x 1024]
        gemm64<4, false><<<dim3(DIMX / 64, ROWS / 64, 1), 256, 0, stream>>>(
            hid + HIDD, 2 * HIDD, 0, W_out, DIMX, 0, outb, DIMX, 0,
            b_out, nullptr, nullptr, nullptr, ROWS, DIMX, HIDD, 0.f);
    }
}

// Round 3
// 801.994 us; speedup vs baseline: 2.9884x; 2.9884x over previous
//
#include <hip/hip_runtime.h>
#include <math.h>

#define DIMX 1024
#define QKD  128
#define HIDD 2048
#define BATCH 4
#define SEQ  2048

typedef __bf16 bf16;
typedef __bf16 bf16x8 __attribute__((ext_vector_type(8)));
typedef __bf16 bf16x4v __attribute__((ext_vector_type(4)));
typedef float f32x4 __attribute__((ext_vector_type(4)));

__device__ __forceinline__ float siluf(float v) { return v / (1.f + expf(-v)); }
__device__ __forceinline__ void splitf(float x, bf16& h, bf16& l) {
    h = (bf16)x;
    l = (bf16)(x - (float)h);
}
__device__ __forceinline__ f32x4 mfma16(bf16x8 a, bf16x8 b, f32x4 c) {
    return __builtin_amdgcn_mfma_f32_16x16x32_bf16(a, b, c, 0, 0, 0);
}

// -------------------- LayerNorm -> split bf16 hi/lo --------------------
__global__ __launch_bounds__(256) void ln_split(const float* __restrict__ x,
                                                const float* __restrict__ scale,
                                                const float* __restrict__ bias,
                                                bf16* __restrict__ xh,
                                                bf16* __restrict__ xl) {
    const int row = blockIdx.x;
    const float4 v = reinterpret_cast<const float4*>(x + (size_t)row * DIMX)[threadIdx.x];
    float s  = v.x + v.y + v.z + v.w;
    float ss = v.x * v.x + v.y * v.y + v.z * v.z + v.w * v.w;
    #pragma unroll
    for (int off = 32; off; off >>= 1) {
        s  += __shfl_down(s, off);
        ss += __shfl_down(ss, off);
    }
    __shared__ float ls[4], lss[4];
    const int wid = threadIdx.x >> 6, lane = threadIdx.x & 63;
    if (lane == 0) { ls[wid] = s; lss[wid] = ss; }
    __syncthreads();
    if (threadIdx.x == 0) {
        float a = ls[0] + ls[1] + ls[2] + ls[3];
        float b = lss[0] + lss[1] + lss[2] + lss[3];
        float mu  = a / DIMX;
        float var = b / DIMX - mu * mu;
        ls[0]  = mu;
        lss[0] = rsqrtf(var + 1e-5f);
    }
    __syncthreads();
    const float mu = ls[0], rs = lss[0];
    const float4 sc = reinterpret_cast<const float4*>(scale)[threadIdx.x];
    const float4 bi = reinterpret_cast<const float4*>(bias)[threadIdx.x];
    float o[4];
    o[0] = (v.x - mu) * rs * sc.x + bi.x;
    o[1] = (v.y - mu) * rs * sc.y + bi.y;
    o[2] = (v.z - mu) * rs * sc.z + bi.z;
    o[3] = (v.w - mu) * rs * sc.w + bi.w;
    bf16x4v h, l;
    #pragma unroll
    for (int i = 0; i < 4; ++i) { bf16 hh, ll; splitf(o[i], hh, ll); h[i] = hh; l[i] = ll; }
    *reinterpret_cast<bf16x4v*>(xh + (size_t)row * DIMX + threadIdx.x * 4) = h;
    *reinterpret_cast<bf16x4v*>(xl + (size_t)row * DIMX + threadIdx.x * 4) = l;
}

// -------------------- transpose + split: W [K][N] fp32 -> T[N][K] bf16 hi/lo ------
__global__ __launch_bounds__(256) void wsplitT(const float* __restrict__ W, int K, int N,
                                               bf16* __restrict__ Th, bf16* __restrict__ Tl) {
    __shared__ float tile[32][33];
    const int bx = blockIdx.x * 32;   // N dir
    const int by = blockIdx.y * 32;   // K dir
    const int tx = threadIdx.x & 31, ty = threadIdx.x >> 5;
    #pragma unroll
    for (int r = 0; r < 32; r += 8)
        tile[ty + r][tx] = W[(size_t)(by + ty + r) * N + bx + tx];
    __syncthreads();
    #pragma unroll
    for (int r = 0; r < 32; r += 8) {
        const float v = tile[tx][ty + r];
        bf16 h, l; splitf(v, h, l);
        Th[(size_t)(bx + ty + r) * K + by + tx] = h;
        Tl[(size_t)(bx + ty + r) * K + by + tx] = l;
    }
}

// -------------------- split-bf16 MFMA GEMM: 128x128x32 tile, 256 threads ----------
// A: [M][K] hi/lo bf16 (lda), B: [N][K] hi/lo bf16 (ldb).  acc fp32.
// EPI 0 (hid):  s=silu(acc+e0[n]); n<HIDD -> vT hi/lo at Oh/Ol[n][m] (ldo);
//                                  n>=HIDD -> gateT fp32 at Fo[n-HIDD][m] (ldf)
// EPI 1 (qk):   s=silu(acc+e0[n]); q=s*e1[n]+e2[n] -> Oh/Ol[m][n];
//                                  k=s*e1[QKD+n]+e2[QKD+n] -> O2h/O2l[m][n]
// EPI 2 (sim):  t=acc*scale; p=relu(t)^2 -> Oh/Ol[m][n]
// EPI 3 (av):   y=acc*gr[n][m] -> Oh/Ol[m][n]
// EPI 4 (out):  Fo[m][n] = acc + e0[n]
template<int EPI>
__global__ __launch_bounds__(256) void gmm(
    const bf16* __restrict__ Ah, const bf16* __restrict__ Al, int lda, long long sA,
    const bf16* __restrict__ Bh, const bf16* __restrict__ Bl, int ldb, long long sB,
    bf16* __restrict__ Oh, bf16* __restrict__ Ol, int ldo, long long sO,
    bf16* __restrict__ O2h, bf16* __restrict__ O2l,
    float* __restrict__ Fo, int ldf,
    const float* __restrict__ e0, const float* __restrict__ e1, const float* __restrict__ e2,
    const float* __restrict__ gr, int ldg, long long sG,
    int K, float scale) {

    __shared__ bf16 Ash[128][40], Asl[128][40], Bsh[128][40], Bsl[128][40];

    const int z = blockIdx.z;
    Ah += (size_t)sA * z;  Al += (size_t)sA * z;
    Bh += (size_t)sB * z;  Bl += (size_t)sB * z;
    if (Oh) { Oh += (size_t)sO * z; Ol += (size_t)sO * z; }
    if (gr) gr += (size_t)sG * z;

    const int t = threadIdx.x;
    const int l = t & 63, wid = t >> 6;
    const int wr = wid >> 1, wc = wid & 1;
    const int bm = blockIdx.y * 128, bn = blockIdx.x * 128;

    // staging assignment: row sm (0..127), 32B chunk cs (swizzled for bank spread)
    const int sm = t >> 1;
    const int cs = (t & 1) ^ ((sm >> 3) & 1);

    const int lr = l & 15, k8 = (l >> 4) * 8;

    f32x4 acc[4][4] = {};

    for (int k0 = 0; k0 < K; k0 += 32) {
        {
            const size_t ao = (size_t)(bm + sm) * lda + k0 + cs * 16;
            const float4 a0 = *reinterpret_cast<const float4*>(Ah + ao);
            const float4 a1 = *reinterpret_cast<const float4*>(Ah + ao + 8);
            const float4 a2 = *reinterpret_cast<const float4*>(Al + ao);
            const float4 a3 = *reinterpret_cast<const float4*>(Al + ao + 8);
            *reinterpret_cast<float4*>(&Ash[sm][cs * 16])     = a0;
            *reinterpret_cast<float4*>(&Ash[sm][cs * 16 + 8]) = a1;
            *reinterpret_cast<float4*>(&Asl[sm][cs * 16])     = a2;
            *reinterpret_cast<float4*>(&Asl[sm][cs * 16 + 8]) = a3;
            const size_t bo = (size_t)(bn + sm) * ldb + k0 + cs * 16;
            const float4 b0 = *reinterpret_cast<const float4*>(Bh + bo);
            const float4 b1 = *reinterpret_cast<const float4*>(Bh + bo + 8);
            const float4 b2 = *reinterpret_cast<const float4*>(Bl + bo);
            const float4 b3 = *reinterpret_cast<const float4*>(Bl + bo + 8);
            *reinterpret_cast<float4*>(&Bsh[sm][cs * 16])     = b0;
            *reinterpret_cast<float4*>(&Bsh[sm][cs * 16 + 8]) = b1;
            *reinterpret_cast<float4*>(&Bsl[sm][cs * 16])     = b2;
            *reinterpret_cast<float4*>(&Bsl[sm][cs * 16 + 8]) = b3;
        }
        __syncthreads();

        bf16x8 bh[4], bl4[4];
        #pragma unroll
        for (int j = 0; j < 4; ++j) {
            bh[j]  = *reinterpret_cast<const bf16x8*>(&Bsh[wc * 64 + j * 16 + lr][k8]);
            bl4[j] = *reinterpret_cast<const bf16x8*>(&Bsl[wc * 64 + j * 16 + lr][k8]);
        }
        #pragma unroll
        for (int i = 0; i < 4; ++i) {
            const bf16x8 ah  = *reinterpret_cast<const bf16x8*>(&Ash[wr * 64 + i * 16 + lr][k8]);
            const bf16x8 al4 = *reinterpret_cast<const bf16x8*>(&Asl[wr * 64 + i * 16 + lr][k8]);
            #pragma unroll
            for (int j = 0; j < 4; ++j) {
                acc[i][j] = mfma16(ah,  bh[j],  acc[i][j]);
                acc[i][j] = mfma16(ah,  bl4[j], acc[i][j]);
                acc[i][j] = mfma16(al4, bh[j],  acc[i][j]);
            }
        }
        __syncthreads();
    }

    // ---- epilogue ----
    #pragma unroll
    for (int i = 0; i < 4; ++i) {
        const int mf = bm + wr * 64 + i * 16 + (l >> 4) * 4;   // rows mf..mf+3
        #pragma unroll
        for (int j = 0; j < 4; ++j) {
            const int nn = bn + wc * 64 + j * 16 + lr;
            const f32x4 a = acc[i][j];
            if constexpr (EPI == 0) {
                float s[4];
                #pragma unroll
                for (int r = 0; r < 4; ++r) s[r] = siluf(a[r] + e0[nn]);
                if (nn < HIDD) {
                    bf16x4v h, lo;
                    #pragma unroll
                    for (int r = 0; r < 4; ++r) { bf16 hh, ll; splitf(s[r], hh, ll); h[r] = hh; lo[r] = ll; }
                    *reinterpret_cast<bf16x4v*>(&Oh[(size_t)nn * ldo + mf]) = h;
                    *reinterpret_cast<bf16x4v*>(&Ol[(size_t)nn * ldo + mf]) = lo;
                } else {
                    float4 g = make_float4(s[0], s[1], s[2], s[3]);
                    *reinterpret_cast<float4*>(&Fo[(size_t)(nn - HIDD) * ldf + mf]) = g;
                }
            } else if constexpr (EPI == 1) {
                #pragma unroll
                for (int r = 0; r < 4; ++r) {
                    const float s = siluf(a[r] + e0[nn]);
                    const float q = s * e1[nn] + e2[nn];
                    const float k = s * e1[QKD + nn] + e2[QKD + nn];
                    bf16 h, lo;
                    splitf(q, h, lo);
                    Oh[(size_t)(mf + r) * ldo + nn] = h;  Ol[(size_t)(mf + r) * ldo + nn] = lo;
                    splitf(k, h, lo);
                    O2h[(size_t)(mf + r) * ldo + nn] = h; O2l[(size_t)(mf + r) * ldo + nn] = lo;
                }
            } else if constexpr (EPI == 2) {
                #pragma unroll
                for (int r = 0; r < 4; ++r) {
                    const float tv = a[r] * scale;
                    const float p = tv > 0.f ? tv * tv : 0.f;
                    bf16 h, lo; splitf(p, h, lo);
                    Oh[(size_t)(mf + r) * ldo + nn] = h;  Ol[(size_t)(mf + r) * ldo + nn] = lo;
                }
            } else if constexpr (EPI == 3) {
                const float4 g = *reinterpret_cast<const float4*>(&gr[(size_t)nn * ldg + mf]);
                const float gv[4] = {g.x, g.y, g.z, g.w};
                #pragma unroll
                for (int r = 0; r < 4; ++r) {
                    const float y = a[r] * gv[r];
                    bf16 h, lo; splitf(y, h, lo);
                    Oh[(size_t)(mf + r) * ldo + nn] = h;  Ol[(size_t)(mf + r) * ldo + nn] = lo;
                }
            } else {
                #pragma unroll
                for (int r = 0; r < 4; ++r)
                    Fo[(size_t)(mf + r) * ldf + nn] = a[r] + e0[nn];
            }
        }
    }
}

extern "C" void kernel_launch(void* const* d_in, const int* in_sizes, int n_in,
                              void* d_out, int out_size, void* d_ws, size_t ws_size,
                              hipStream_t stream) {
    const float* x        = (const float*)d_in[0];
    const float* ln_scale = (const float*)d_in[1];
    const float* ln_bias  = (const float*)d_in[2];
    const float* W_hidden = (const float*)d_in[3];
    const float* b_hidden = (const float*)d_in[4];
    const float* W_qk     = (const float*)d_in[5];
    const float* b_qk     = (const float*)d_in[6];
    const float* os_w     = (const float*)d_in[7];
    const float* os_b     = (const float*)d_in[8];
    const float* W_out    = (const float*)d_in[9];
    const float* b_out    = (const float*)d_in[10];
    float* out = (float*)d_out;

    // ---- workspace carve ----
    char* p = (char*)d_ws;
    bf16* WhTh  = (bf16*)p; p += (size_t)4096 * 1024 * 2;
    bf16* WhTl  = (bf16*)p; p += (size_t)4096 * 1024 * 2;
    bf16* WqkTh = (bf16*)p; p += (size_t)QKD * 1024 * 2;
    bf16* WqkTl = (bf16*)p; p += (size_t)QKD * 1024 * 2;
    bf16* WoTh  = (bf16*)p; p += (size_t)1024 * HIDD * 2;
    bf16* WoTl  = (bf16*)p; p += (size_t)1024 * HIDD * 2;
    char* cbase = p;
    const size_t wBytes = (size_t)(p - (char*)d_ws);
    const size_t perB   = 69206016ull;   // per-batch chunk bytes
    int NB = (ws_size >= wBytes + 4 * perB) ? 4 : (ws_size >= wBytes + 2 * perB) ? 2 : 1;

    // ---- one-time weight transpose+split ----
    wsplitT<<<dim3(4096 / 32, 1024 / 32), 256, 0, stream>>>(W_hidden, DIMX, 2 * HIDD, WhTh, WhTl);
    wsplitT<<<dim3(QKD / 32, 1024 / 32), 256, 0, stream>>>(W_qk, DIMX, QKD, WqkTh, WqkTl);
    wsplitT<<<dim3(1024 / 32, 2048 / 32), 256, 0, stream>>>(W_out, HIDD, DIMX, WoTh, WoTl);

    for (int b0 = 0; b0 < BATCH; b0 += NB) {
        const int nb = NB;
        const int ROWS = nb * SEQ;
        const float* xb = x + (size_t)b0 * SEQ * DIMX;
        float* outb = out + (size_t)b0 * SEQ * DIMX;

        // xn hi/lo live inside the d_out chunk region (exact byte fit)
        bf16* xh = (bf16*)outb;
        bf16* xl = xh + (size_t)ROWS * DIMX;

        char* q = cbase;
        bf16* qh   = (bf16*)q; q += (size_t)ROWS * QKD * 2;
        bf16* ql   = (bf16*)q; q += (size_t)ROWS * QKD * 2;
        bf16* kh   = (bf16*)q; q += (size_t)ROWS * QKD * 2;
        bf16* kl   = (bf16*)q; q += (size_t)ROWS * QKD * 2;
        bf16* vTh  = (bf16*)q; q += (size_t)HIDD * ROWS * 2;
        bf16* vTl  = (bf16*)q; q += (size_t)HIDD * ROWS * 2;
        float* gateT = (float*)q; q += (size_t)HIDD * ROWS * 4;
        bf16* ath  = (bf16*)q; q += (size_t)nb * SEQ * SEQ * 2;
        bf16* atl  = (bf16*)q; q += (size_t)nb * SEQ * SEQ * 2;
        bf16* yh   = (bf16*)q; q += (size_t)ROWS * HIDD * 2;
        bf16* yl   = (bf16*)q; q += (size_t)ROWS * HIDD * 2;

        // 1) LayerNorm -> xn hi/lo
        ln_split<<<ROWS, 256, 0, stream>>>(xb, ln_scale, ln_bias, xh, xl);

        // 2) hid GEMM: [ROWS x 4096] = xn @ W_hidden; epilogue silu -> vT hi/lo + gateT
        gmm<0><<<dim3(4096 / 128, ROWS / 128, 1), 256, 0, stream>>>(
            xh, xl, DIMX, 0, WhTh, WhTl, DIMX, 0,
            vTh, vTl, ROWS, 0, nullptr, nullptr,
            gateT, ROWS, b_hidden, nullptr, nullptr, nullptr, 0, 0,
            DIMX, 0.f);

        // 3) qk GEMM: [ROWS x 128]; epilogue silu + os scale -> q,k hi/lo
        gmm<1><<<dim3(1, ROWS / 128, 1), 256, 0, stream>>>(
            xh, xl, DIMX, 0, WqkTh, WqkTl, DIMX, 0,
            qh, ql, QKD, 0, kh, kl,
            nullptr, 0, b_qk, os_w, os_b, nullptr, 0, 0,
            DIMX, 0.f);

        // 4) sim: [SEQ x SEQ] per batch = q @ k^T / n; relu^2 -> attn hi/lo
        gmm<2><<<dim3(SEQ / 128, SEQ / 128, nb), 256, 0, stream>>>(
            qh, ql, QKD, (long long)SEQ * QKD, kh, kl, QKD, (long long)SEQ * QKD,
            ath, atl, SEQ, (long long)SEQ * SEQ, nullptr, nullptr,
            nullptr, 0, nullptr, nullptr, nullptr, nullptr, 0, 0,
            QKD, 1.0f / SEQ);

        // 5) attn@v: [SEQ x HIDD] per batch; epilogue * gate -> y hi/lo
        gmm<3><<<dim3(HIDD / 128, SEQ / 128, nb), 256, 0, stream>>>(
            ath, atl, SEQ, (long long)SEQ * SEQ, vTh, vTl, ROWS, (long long)SEQ,
            yh, yl, HIDD, (long long)SEQ * HIDD, nullptr, nullptr,
            nullptr, 0, nullptr, nullptr, nullptr, gateT, ROWS, (long long)SEQ,
            SEQ, 0.f);

        // 6) out: [ROWS x 1024] = y @ W_out + b_out -> fp32 d_out
        gmm<4><<<dim3(DIMX / 128, ROWS / 128, 1), 256, 0, stream>>>(
            yh, yl, HIDD, 0, WoTh, WoTl, HIDD, 0,
            nullptr, nullptr, 0, 0, nullptr, nullptr,
            outb, DIMX, b_out, nullptr, nullptr, nullptr, 0, 0,
            HIDD, 0.f);
    }
}

// Round 4
// 375.032 us; speedup vs baseline: 6.3906x; 2.1385x over previous
//
#include <hip/hip_runtime.h>
#include <math.h>

#define DIMX 1024
#define QKD  128
#define HIDD 2048
#define BATCH 4
#define SEQ  2048

typedef __bf16 bf16;
typedef __bf16 bf16x8 __attribute__((ext_vector_type(8)));
typedef __bf16 bf16x4v __attribute__((ext_vector_type(4)));
typedef float f32x4 __attribute__((ext_vector_type(4)));

__device__ __forceinline__ float siluf(float v) { return v / (1.f + expf(-v)); }
__device__ __forceinline__ void splitf(float x, bf16& h, bf16& l) {
    h = (bf16)x;
    l = (bf16)(x - (float)h);
}
__device__ __forceinline__ f32x4 mfma16(bf16x8 a, bf16x8 b, f32x4 c) {
    return __builtin_amdgcn_mfma_f32_16x16x32_bf16(a, b, c, 0, 0, 0);
}

typedef __attribute__((address_space(1))) const void cg_void;
typedef __attribute__((address_space(3))) void lds_void_t;
__device__ __forceinline__ void gload16(const bf16* g, bf16* l) {
    __builtin_amdgcn_global_load_lds((cg_void*)g, (lds_void_t*)l, 16, 0, 0);
}

// -------------------- LayerNorm -> split bf16 hi/lo --------------------
__global__ __launch_bounds__(256) void ln_split(const float* __restrict__ x,
                                                const float* __restrict__ scale,
                                                const float* __restrict__ bias,
                                                bf16* __restrict__ xh,
                                                bf16* __restrict__ xl) {
    const int row = blockIdx.x;
    const float4 v = reinterpret_cast<const float4*>(x + (size_t)row * DIMX)[threadIdx.x];
    float s  = v.x + v.y + v.z + v.w;
    float ss = v.x * v.x + v.y * v.y + v.z * v.z + v.w * v.w;
    #pragma unroll
    for (int off = 32; off; off >>= 1) {
        s  += __shfl_down(s, off);
        ss += __shfl_down(ss, off);
    }
    __shared__ float ls[4], lss[4];
    const int wid = threadIdx.x >> 6, lane = threadIdx.x & 63;
    if (lane == 0) { ls[wid] = s; lss[wid] = ss; }
    __syncthreads();
    if (threadIdx.x == 0) {
        float a = ls[0] + ls[1] + ls[2] + ls[3];
        float b = lss[0] + lss[1] + lss[2] + lss[3];
        float mu  = a / DIMX;
        float var = b / DIMX - mu * mu;
        ls[0]  = mu;
        lss[0] = rsqrtf(var + 1e-5f);
    }
    __syncthreads();
    const float mu = ls[0], rs = lss[0];
    const float4 sc = reinterpret_cast<const float4*>(scale)[threadIdx.x];
    const float4 bi = reinterpret_cast<const float4*>(bias)[threadIdx.x];
    float o[4];
    o[0] = (v.x - mu) * rs * sc.x + bi.x;
    o[1] = (v.y - mu) * rs * sc.y + bi.y;
    o[2] = (v.z - mu) * rs * sc.z + bi.z;
    o[3] = (v.w - mu) * rs * sc.w + bi.w;
    bf16x4v h, l;
    #pragma unroll
    for (int i = 0; i < 4; ++i) { bf16 hh, ll; splitf(o[i], hh, ll); h[i] = hh; l[i] = ll; }
    *reinterpret_cast<bf16x4v*>(xh + (size_t)row * DIMX + threadIdx.x * 4) = h;
    *reinterpret_cast<bf16x4v*>(xl + (size_t)row * DIMX + threadIdx.x * 4) = l;
}

// ------------- transpose + split: W [K][N] fp32 -> T[N][K] bf16 hi(/lo) -------------
__global__ __launch_bounds__(256) void wsplitT(const float* __restrict__ W, int K, int N,
                                               bf16* __restrict__ Th, bf16* __restrict__ Tl) {
    __shared__ float tile[32][33];
    const int bx = blockIdx.x * 32;   // N dir
    const int by = blockIdx.y * 32;   // K dir
    const int tx = threadIdx.x & 31, ty = threadIdx.x >> 5;
    #pragma unroll
    for (int r = 0; r < 32; r += 8)
        tile[ty + r][tx] = W[(size_t)(by + ty + r) * N + bx + tx];
    __syncthreads();
    #pragma unroll
    for (int r = 0; r < 32; r += 8) {
        const float v = tile[tx][ty + r];
        bf16 h, l; splitf(v, h, l);
        Th[(size_t)(bx + ty + r) * K + by + tx] = h;
        if (Tl) Tl[(size_t)(bx + ty + r) * K + by + tx] = l;
    }
}

// ---------------- MFMA GEMM: TMxTN tile (TM=MI*32, TN=NI*32), 256 thr, 4 waves ------
// A [M][K] (lda), B [N][K] (ldb), fp32 accum.
// SPLIT: 3-product hi/lo via K'=3K: slices (Ah,Bh),(Al,Bh),(Ah,Bl)
// EPI 0 (hid):  s=silu(acc+e0[n]); n<HIDD -> vT bf16 at O[n][m]; else gateT bf16 at G[n-HIDD][m]
// EPI 1 (qk):   s=silu(acc+e0[n]); q=s*e1[n]+e2[n] -> split O/O2[m][n]; k=s*e1[QKD+n]+e2[QKD+n] -> split O3/O4
// EPI 2 (sim):  p=relu(acc*scale)^2 -> bf16 O[m][n]
// EPI 3 (av):   y=acc*G[n][m] -> bf16 O[m][n]
// EPI 4 (out):  F[m][n] = acc + e0[n]  (fp32)
template<int EPI, bool SPLIT, int MI, int NI>
__global__ __launch_bounds__(256) void gmm(
    const bf16* __restrict__ Ah, const bf16* __restrict__ Al, int lda, long long sA,
    const bf16* __restrict__ Bh, const bf16* __restrict__ Bl, int ldb, long long sB,
    bf16* __restrict__ O, int ldo, long long sO,
    bf16* __restrict__ O2, bf16* __restrict__ O3, bf16* __restrict__ O4,
    bf16* __restrict__ G, int ldg, long long sG,
    float* __restrict__ F, int ldf,
    const float* __restrict__ e0, const float* __restrict__ e1, const float* __restrict__ e2,
    int K, float scale) {

    constexpr int TM = MI * 32, TN = NI * 32;
    constexpr int CHA = TM / 64, CHB = TN / 64;
    __shared__ __align__(16) bf16 As[TM * 32];
    __shared__ __align__(16) bf16 Bs[TN * 32];

    const int z = blockIdx.z;
    Ah += (size_t)sA * z;
    if (SPLIT) Al += (size_t)sA * z;
    Bh += (size_t)sB * z;
    if (SPLIT) Bl += (size_t)sB * z;
    if (O) O += (size_t)sO * z;
    if (G) G += (size_t)sG * z;

    const int t = threadIdx.x;
    const int l = t & 63, w = t >> 6;
    const int wr = w >> 1, wc = w & 1;
    const int lr = l & 15, ls = l >> 4;
    const int bm = blockIdx.y * TM, bn = blockIdx.x * TN;

    f32x4 acc[MI][NI] = {};
    const int KT = SPLIT ? 3 * K : K;

    for (int k0 = 0; k0 < KT; k0 += 32) {
        const bf16 *pA, *pB;
        int kin;
        if constexpr (SPLIT) {
            if (k0 < K)          { pA = Ah; pB = Bh; kin = k0; }
            else if (k0 < 2 * K) { pA = Al; pB = Bh; kin = k0 - K; }
            else                 { pA = Ah; pB = Bl; kin = k0 - 2 * K; }
        } else { pA = Ah; pB = Bh; kin = k0; }

        #pragma unroll
        for (int c = 0; c < CHA; ++c) {
            const int idx = c * 256 + w * 64 + l;
            const int row = idx >> 2;
            const int sg = (idx & 3) ^ ((row >> 1) & 3);
            gload16(pA + (size_t)(bm + row) * lda + kin + sg * 8,
                    As + (size_t)(c * 256 + w * 64) * 8);
        }
        #pragma unroll
        for (int c = 0; c < CHB; ++c) {
            const int idx = c * 256 + w * 64 + l;
            const int row = idx >> 2;
            const int sg = (idx & 3) ^ ((row >> 1) & 3);
            gload16(pB + (size_t)(bn + row) * ldb + kin + sg * 8,
                    Bs + (size_t)(c * 256 + w * 64) * 8);
        }
        __syncthreads();

        bf16x8 bfr[NI];
        #pragma unroll
        for (int j = 0; j < NI; ++j) {
            const int row = wc * (NI * 16) + j * 16 + lr;
            const int sl = ls ^ ((row >> 1) & 3);
            bfr[j] = *reinterpret_cast<const bf16x8*>(&Bs[row * 32 + sl * 8]);
        }
        #pragma unroll
        for (int i = 0; i < MI; ++i) {
            const int row = wr * (MI * 16) + i * 16 + lr;
            const int sl = ls ^ ((row >> 1) & 3);
            const bf16x8 af = *reinterpret_cast<const bf16x8*>(&As[row * 32 + sl * 8]);
            #pragma unroll
            for (int j = 0; j < NI; ++j)
                acc[i][j] = mfma16(af, bfr[j], acc[i][j]);
        }
        __syncthreads();
    }

    // ---- epilogue ----
    #pragma unroll
    for (int i = 0; i < MI; ++i) {
        const int mf = bm + wr * (MI * 16) + i * 16 + ls * 4;   // rows mf..mf+3
        #pragma unroll
        for (int j = 0; j < NI; ++j) {
            const int nn = bn + wc * (NI * 16) + j * 16 + lr;
            const f32x4 a = acc[i][j];
            if constexpr (EPI == 0) {
                float s[4];
                #pragma unroll
                for (int r = 0; r < 4; ++r) s[r] = siluf(a[r] + e0[nn]);
                bf16x4v h;
                #pragma unroll
                for (int r = 0; r < 4; ++r) h[r] = (bf16)s[r];
                if (nn < HIDD)
                    *reinterpret_cast<bf16x4v*>(&O[(size_t)nn * ldo + mf]) = h;
                else
                    *reinterpret_cast<bf16x4v*>(&G[(size_t)(nn - HIDD) * ldg + mf]) = h;
            } else if constexpr (EPI == 1) {
                #pragma unroll
                for (int r = 0; r < 4; ++r) {
                    const float s = siluf(a[r] + e0[nn]);
                    const float q = s * e1[nn] + e2[nn];
                    const float k = s * e1[QKD + nn] + e2[QKD + nn];
                    bf16 h, lo;
                    splitf(q, h, lo);
                    O[(size_t)(mf + r) * ldo + nn] = h;  O2[(size_t)(mf + r) * ldo + nn] = lo;
                    splitf(k, h, lo);
                    O3[(size_t)(mf + r) * ldo + nn] = h; O4[(size_t)(mf + r) * ldo + nn] = lo;
                }
            } else if constexpr (EPI == 2) {
                #pragma unroll
                for (int r = 0; r < 4; ++r) {
                    const float tv = a[r] * scale;
                    const float p = tv > 0.f ? tv * tv : 0.f;
                    O[(size_t)(mf + r) * ldo + nn] = (bf16)p;
                }
            } else if constexpr (EPI == 3) {
                const bf16x4v g4 = *reinterpret_cast<const bf16x4v*>(&G[(size_t)nn * ldg + mf]);
                #pragma unroll
                for (int r = 0; r < 4; ++r) {
                    const float y = a[r] * (float)g4[r];
                    O[(size_t)(mf + r) * ldo + nn] = (bf16)y;
                }
            } else {
                #pragma unroll
                for (int r = 0; r < 4; ++r)
                    F[(size_t)(mf + r) * ldf + nn] = a[r] + e0[nn];
            }
        }
    }
}

extern "C" void kernel_launch(void* const* d_in, const int* in_sizes, int n_in,
                              void* d_out, int out_size, void* d_ws, size_t ws_size,
                              hipStream_t stream) {
    const float* x        = (const float*)d_in[0];
    const float* ln_scale = (const float*)d_in[1];
    const float* ln_bias  = (const float*)d_in[2];
    const float* W_hidden = (const float*)d_in[3];
    const float* b_hidden = (const float*)d_in[4];
    const float* W_qk     = (const float*)d_in[5];
    const float* b_qk     = (const float*)d_in[6];
    const float* os_w     = (const float*)d_in[7];
    const float* os_b     = (const float*)d_in[8];
    const float* W_out    = (const float*)d_in[9];
    const float* b_out    = (const float*)d_in[10];
    float* out = (float*)d_out;

    // ---- weight prep area ----
    char* p = (char*)d_ws;
    bf16* WhTh  = (bf16*)p; p += (size_t)4096 * 1024 * 2;   // [4096][1024] plain
    bf16* WqkTh = (bf16*)p; p += (size_t)128 * 1024 * 2;    // [128][1024] hi
    bf16* WqkTl = (bf16*)p; p += (size_t)128 * 1024 * 2;    // lo
    bf16* WoTh  = (bf16*)p; p += (size_t)1024 * 2048 * 2;   // [1024][2048] plain

    wsplitT<<<dim3(4096 / 32, 1024 / 32), 256, 0, stream>>>(W_hidden, 1024, 4096, WhTh, nullptr);
    wsplitT<<<dim3(128 / 32, 1024 / 32), 256, 0, stream>>>(W_qk, 1024, 128, WqkTh, WqkTl);
    wsplitT<<<dim3(1024 / 32, 2048 / 32), 256, 0, stream>>>(W_out, 2048, 1024, WoTh, nullptr);

    const size_t used = (size_t)(p - (char*)d_ws);
    const size_t qkB   = (size_t)4 * 8192 * 128 * 2;       // q,k hi/lo
    const size_t vTB   = (size_t)2048 * 8192 * 2;
    const size_t gateB = (size_t)2048 * 8192 * 2;
    const size_t attnB = (size_t)4 * 2048 * 2048 * 2;
    const size_t yB    = (size_t)8192 * 2048 * 2;
    const bool allb = (ws_size >= used + qkB + vTB + gateB + attnB + yB + (1u << 20));

    if (allb) {
        // ---------------- all-batch mode ----------------
        bf16* xh = (bf16*)out;                      // d_out doubles as xn hi/lo
        bf16* xl = xh + (size_t)8192 * 1024;
        bf16* qh   = (bf16*)p; p += (size_t)8192 * 128 * 2;
        bf16* ql   = (bf16*)p; p += (size_t)8192 * 128 * 2;
        bf16* kh   = (bf16*)p; p += (size_t)8192 * 128 * 2;
        bf16* kl   = (bf16*)p; p += (size_t)8192 * 128 * 2;
        bf16* vT   = (bf16*)p; p += vTB;            // [2048][8192]
        bf16* gateT= (bf16*)p; p += gateB;          // [2048][8192]
        bf16* attn = (bf16*)p; p += attnB;          // [4][2048][2048]
        bf16* y    = (bf16*)p; p += yB;             // [8192][2048]

        ln_split<<<8192, 256, 0, stream>>>(x, ln_scale, ln_bias, xh, xl);

        // hid (plain): [8192 x 4096] -> vT + gateT
        gmm<0, false, 4, 4><<<dim3(4096 / 128, 8192 / 128), 256, 0, stream>>>(
            xh, nullptr, 1024, 0, WhTh, nullptr, 1024, 0,
            vT, 8192, 0, nullptr, nullptr, nullptr,
            gateT, 8192, 0, nullptr, 0,
            b_hidden, nullptr, nullptr, 1024, 0.f);

        // qk (split): [8192 x 128] -> q,k hi/lo
        gmm<1, true, 2, 2><<<dim3(128 / 64, 8192 / 64), 256, 0, stream>>>(
            xh, xl, 1024, 0, WqkTh, WqkTl, 1024, 0,
            qh, 128, 0, ql, kh, kl,
            nullptr, 0, 0, nullptr, 0,
            b_qk, os_w, os_b, 1024, 0.f);

        // sim (split): per-batch [2048 x 2048], z=4
        gmm<2, true, 4, 4><<<dim3(16, 16, 4), 256, 0, stream>>>(
            qh, ql, 128, (long long)2048 * 128, kh, kl, 128, (long long)2048 * 128,
            attn, 2048, (long long)2048 * 2048, nullptr, nullptr, nullptr,
            nullptr, 0, 0, nullptr, 0,
            nullptr, nullptr, nullptr, 128, 1.0f / SEQ);

        // av (plain): [2048 x 2048] per batch; B = vT cols z*2048, gate mult
        gmm<3, false, 4, 4><<<dim3(16, 16, 4), 256, 0, stream>>>(
            attn, nullptr, 2048, (long long)2048 * 2048,
            vT, nullptr, 8192, 2048,
            y, 2048, (long long)2048 * 2048, nullptr, nullptr, nullptr,
            gateT, 8192, 2048, nullptr, 0,
            nullptr, nullptr, nullptr, 2048, 0.f);

        // out (plain): [8192 x 1024] fp32 -> d_out
        gmm<4, false, 4, 4><<<dim3(1024 / 128, 8192 / 128), 256, 0, stream>>>(
            y, nullptr, 2048, 0, WoTh, nullptr, 2048, 0,
            nullptr, 0, 0, nullptr, nullptr, nullptr,
            nullptr, 0, 0, out, 1024,
            b_out, nullptr, nullptr, 2048, 0.f);
    } else {
        // ---------------- per-batch mode (low workspace) ----------------
        bf16* xh = (bf16*)p; p += (size_t)8192 * 1024 * 2;
        bf16* xl = (bf16*)p; p += (size_t)8192 * 1024 * 2;
        bf16* qh   = (bf16*)p; p += (size_t)2048 * 128 * 2;
        bf16* ql   = (bf16*)p; p += (size_t)2048 * 128 * 2;
        bf16* kh   = (bf16*)p; p += (size_t)2048 * 128 * 2;
        bf16* kl   = (bf16*)p; p += (size_t)2048 * 128 * 2;
        bf16* vT   = (bf16*)p; p += (size_t)2048 * 2048 * 2;
        bf16* gateT= (bf16*)p; p += (size_t)2048 * 2048 * 2;
        bf16* attn = (bf16*)p; p += (size_t)2048 * 2048 * 2;
        bf16* y    = (bf16*)p; p += (size_t)2048 * 2048 * 2;

        ln_split<<<8192, 256, 0, stream>>>(x, ln_scale, ln_bias, xh, xl);

        for (int b = 0; b < BATCH; ++b) {
            const bf16* xhb = xh + (size_t)b * 2048 * 1024;
            const bf16* xlb = xl + (size_t)b * 2048 * 1024;

            gmm<0, false, 4, 4><<<dim3(4096 / 128, 2048 / 128), 256, 0, stream>>>(
                xhb, nullptr, 1024, 0, WhTh, nullptr, 1024, 0,
                vT, 2048, 0, nullptr, nullptr, nullptr,
                gateT, 2048, 0, nullptr, 0,
                b_hidden, nullptr, nullptr, 1024, 0.f);

            gmm<1, true, 2, 2><<<dim3(128 / 64, 2048 / 64), 256, 0, stream>>>(
                xhb, xlb, 1024, 0, WqkTh, WqkTl, 1024, 0,
                qh, 128, 0, ql, kh, kl,
                nullptr, 0, 0, nullptr, 0,
                b_qk, os_w, os_b, 1024, 0.f);

            gmm<2, true, 4, 4><<<dim3(16, 16, 1), 256, 0, stream>>>(
                qh, ql, 128, 0, kh, kl, 128, 0,
                attn, 2048, 0, nullptr, nullptr, nullptr,
                nullptr, 0, 0, nullptr, 0,
                nullptr, nullptr, nullptr, 128, 1.0f / SEQ);

            gmm<3, false, 4, 4><<<dim3(16, 16, 1), 256, 0, stream>>>(
                attn, nullptr, 2048, 0,
                vT, nullptr, 2048, 0,
                y, 2048, 0, nullptr, nullptr, nullptr,
                gateT, 2048, 0, nullptr, 0,
                nullptr, nullptr, nullptr, 2048, 0.f);

            gmm<4, false, 4, 4><<<dim3(1024 / 128, 2048 / 128), 256, 0, stream>>>(
                y, nullptr, 2048, 0, WoTh, nullptr, 2048, 0,
                nullptr, 0, 0, nullptr, nullptr, nullptr,
                nullptr, 0, 0, out + (size_t)b * 2048 * 1024, 1024,
                b_out, nullptr, nullptr, 2048, 0.f);
        }
    }
}

// Round 5
// 305.969 us; speedup vs baseline: 7.8331x; 1.2257x over previous
//
#include <hip/hip_runtime.h>
#include <math.h>

#define DIMX 1024
#define QKD  128
#define HIDD 2048
#define BATCH 4
#define SEQ  2048

typedef __bf16 bf16;
typedef __bf16 bf16x8 __attribute__((ext_vector_type(8)));
typedef __bf16 bf16x4v __attribute__((ext_vector_type(4)));
typedef float f32x4 __attribute__((ext_vector_type(4)));

__device__ __forceinline__ float siluf(float v) { return v / (1.f + expf(-v)); }
__device__ __forceinline__ void splitf(float x, bf16& h, bf16& l) {
    h = (bf16)x;
    l = (bf16)(x - (float)h);
}
__device__ __forceinline__ f32x4 mfma16(bf16x8 a, bf16x8 b, f32x4 c) {
    return __builtin_amdgcn_mfma_f32_16x16x32_bf16(a, b, c, 0, 0, 0);
}

typedef __attribute__((address_space(1))) const void cg_void;
typedef __attribute__((address_space(3))) void lds_void_t;
__device__ __forceinline__ void gload16(const bf16* g, bf16* l) {
    __builtin_amdgcn_global_load_lds((cg_void*)g, (lds_void_t*)l, 16, 0, 0);
}

template<int N> __device__ __forceinline__ void wait_vm() {
    if constexpr (N == 0)  asm volatile("s_waitcnt vmcnt(0)" ::: "memory");
    if constexpr (N == 3)  asm volatile("s_waitcnt vmcnt(3)" ::: "memory");
    if constexpr (N == 4)  asm volatile("s_waitcnt vmcnt(4)" ::: "memory");
    if constexpr (N == 6)  asm volatile("s_waitcnt vmcnt(6)" ::: "memory");
    if constexpr (N == 8)  asm volatile("s_waitcnt vmcnt(8)" ::: "memory");
    if constexpr (N == 9)  asm volatile("s_waitcnt vmcnt(9)" ::: "memory");
    if constexpr (N == 12) asm volatile("s_waitcnt vmcnt(12)" ::: "memory");
}

// -------------------- LayerNorm -> split bf16 hi/lo --------------------
__global__ __launch_bounds__(256) void ln_split(const float* __restrict__ x,
                                                const float* __restrict__ scale,
                                                const float* __restrict__ bias,
                                                bf16* __restrict__ xh,
                                                bf16* __restrict__ xl) {
    const int row = blockIdx.x;
    const float4 v = reinterpret_cast<const float4*>(x + (size_t)row * DIMX)[threadIdx.x];
    float s  = v.x + v.y + v.z + v.w;
    float ss = v.x * v.x + v.y * v.y + v.z * v.z + v.w * v.w;
    #pragma unroll
    for (int off = 32; off; off >>= 1) {
        s  += __shfl_down(s, off);
        ss += __shfl_down(ss, off);
    }
    __shared__ float ls[4], lss[4];
    const int wid = threadIdx.x >> 6, lane = threadIdx.x & 63;
    if (lane == 0) { ls[wid] = s; lss[wid] = ss; }
    __syncthreads();
    if (threadIdx.x == 0) {
        float a = ls[0] + ls[1] + ls[2] + ls[3];
        float b = lss[0] + lss[1] + lss[2] + lss[3];
        float mu  = a / DIMX;
        float var = b / DIMX - mu * mu;
        ls[0]  = mu;
        lss[0] = rsqrtf(var + 1e-5f);
    }
    __syncthreads();
    const float mu = ls[0], rs = lss[0];
    const float4 sc = reinterpret_cast<const float4*>(scale)[threadIdx.x];
    const float4 bi = reinterpret_cast<const float4*>(bias)[threadIdx.x];
    float o[4];
    o[0] = (v.x - mu) * rs * sc.x + bi.x;
    o[1] = (v.y - mu) * rs * sc.y + bi.y;
    o[2] = (v.z - mu) * rs * sc.z + bi.z;
    o[3] = (v.w - mu) * rs * sc.w + bi.w;
    bf16x4v h, l;
    #pragma unroll
    for (int i = 0; i < 4; ++i) { bf16 hh, ll; splitf(o[i], hh, ll); h[i] = hh; l[i] = ll; }
    *reinterpret_cast<bf16x4v*>(xh + (size_t)row * DIMX + threadIdx.x * 4) = h;
    *reinterpret_cast<bf16x4v*>(xl + (size_t)row * DIMX + threadIdx.x * 4) = l;
}

// ------------- transpose + split: W [K][N] fp32 -> T[N][K] bf16 hi(/lo) -------------
__global__ __launch_bounds__(256) void wsplitT(const float* __restrict__ W, int K, int N,
                                               bf16* __restrict__ Th, bf16* __restrict__ Tl) {
    __shared__ float tile[32][33];
    const int bx = blockIdx.x * 32;   // N dir
    const int by = blockIdx.y * 32;   // K dir
    const int tx = threadIdx.x & 31, ty = threadIdx.x >> 5;
    #pragma unroll
    for (int r = 0; r < 32; r += 8)
        tile[ty + r][tx] = W[(size_t)(by + ty + r) * N + bx + tx];
    __syncthreads();
    #pragma unroll
    for (int r = 0; r < 32; r += 8) {
        const float v = tile[tx][ty + r];
        bf16 h, l; splitf(v, h, l);
        Th[(size_t)(bx + ty + r) * K + by + tx] = h;
        if (Tl) Tl[(size_t)(bx + ty + r) * K + by + tx] = l;
    }
}

// =====================================================================
// gmm2: deep-pipelined MFMA GEMM.  BM=256, BK=32, 512 threads (8 waves,
// 2Mx4N), 4-deep LDS ring, depth-3 prefetch, counted vmcnt, setprio.
// A [M][K] (lda), B [N][K] (ldb), fp32 accum.
// EPI 0 (hid): s=silu(acc+e0[n]); n<HIDD -> O[n][m] (vT), else G[n-HIDD][m] (gateT)
// EPI 3 (av):  y = acc * G[n][m] -> O[m][n] bf16
// EPI 4 (out): F[m][n] = acc + e0[n]  fp32
// =====================================================================
template<int EPI, int BN>
__global__ __launch_bounds__(512) void gmm2(
    const bf16* __restrict__ A, int lda, long long sA,
    const bf16* __restrict__ B, int ldb, long long sB,
    bf16* __restrict__ O, int ldo, long long sO,
    bf16* __restrict__ G, int ldg, long long sG,
    float* __restrict__ F, int ldf,
    const float* __restrict__ e0,
    int K) {

    constexpr int BM = 256, BK = 32;
    constexpr int AE = BM * BK;            // 8192 bf16
    constexpr int BE = BN * BK;
    constexpr int CHA = AE / (512 * 8);    // 2
    constexpr int CHB = BE / (512 * 8);    // 2 (BN=256) or 1 (BN=128)
    constexpr int L = CHA + CHB;           // loads per thread per tile
    constexpr int WN = BN / 4;             // per-wave cols
    constexpr int MI = 8, NI = WN / 16;

    __shared__ __align__(16) bf16 lds[4 * (AE + BE)];

    const int z = blockIdx.z;
    A += (size_t)sA * z;
    B += (size_t)sB * z;
    bf16* Oz = O ? O + (size_t)sO * z : nullptr;
    bf16* Gz = G ? G + (size_t)sG * z : nullptr;

    const int tid = threadIdx.x;
    const int l = tid & 63, w = tid >> 6;
    const int wr = w >> 2, wc = w & 3;          // 2 x 4 wave grid
    const int lr = l & 15, ls4 = l >> 4;
    const int bm = blockIdx.y * BM, bn = blockIdx.x * BN;

    // per-thread staging source pointers (slot-XOR pre-swizzled global)
    const bf16* aptr[CHA];
    #pragma unroll
    for (int c = 0; c < CHA; ++c) {
        const int flat = c * 512 + tid;
        const int row = flat >> 2;
        const int slot = (flat & 3) ^ ((row >> 1) & 3);
        aptr[c] = A + (size_t)(bm + row) * lda + slot * 8;
    }
    const bf16* bptr[CHB];
    #pragma unroll
    for (int c = 0; c < CHB; ++c) {
        const int flat = c * 512 + tid;
        const int row = flat >> 2;
        const int slot = (flat & 3) ^ ((row >> 1) & 3);
        bptr[c] = B + (size_t)(bn + row) * ldb + slot * 8;
    }

    // fragment ds_read offsets (swizzled to match)
    int aoff[MI], boff[NI];
    #pragma unroll
    for (int i = 0; i < MI; ++i) {
        const int row = wr * 128 + i * 16 + lr;
        aoff[i] = row * BK + (ls4 ^ ((row >> 1) & 3)) * 8;
    }
    #pragma unroll
    for (int j = 0; j < NI; ++j) {
        const int row = wc * WN + j * 16 + lr;
        boff[j] = row * BK + (ls4 ^ ((row >> 1) & 3)) * 8;
    }

    const int NT = K / BK;
    f32x4 acc[MI][NI] = {};

    auto stage = [&](int tile) {
        const int buf = tile & 3;
        bf16* ab = lds + buf * (AE + BE);
        bf16* bb = ab + AE;
        #pragma unroll
        for (int c = 0; c < CHA; ++c)
            gload16(aptr[c] + tile * BK, ab + (c * 512 + w * 64) * 8);
        #pragma unroll
        for (int c = 0; c < CHB; ++c)
            gload16(bptr[c] + tile * BK, bb + (c * 512 + w * 64) * 8);
    };

    stage(0);
    stage(1);
    stage(2);

    for (int t = 0; t < NT; ++t) {
        if (t + 3 < NT) stage(t + 3);
        const int ahead = NT - 1 - t;
        if (ahead >= 3)      wait_vm<3 * L>();   // my tile-t loads landed
        else if (ahead == 2) wait_vm<2 * L>();
        else if (ahead == 1) wait_vm<L>();
        else                 wait_vm<0>();
        __builtin_amdgcn_s_barrier();            // all waves' tile-t landed
        __builtin_amdgcn_sched_barrier(0);

        const int buf = t & 3;
        const bf16* ab = lds + buf * (AE + BE);
        const bf16* bb = ab + AE;
        bf16x8 bfr[NI], afr[MI];
        #pragma unroll
        for (int j = 0; j < NI; ++j)
            bfr[j] = *reinterpret_cast<const bf16x8*>(&bb[boff[j]]);
        #pragma unroll
        for (int i = 0; i < MI; ++i)
            afr[i] = *reinterpret_cast<const bf16x8*>(&ab[aoff[i]]);
        __builtin_amdgcn_s_setprio(1);
        #pragma unroll
        for (int i = 0; i < MI; ++i)
            #pragma unroll
            for (int j = 0; j < NI; ++j)
                acc[i][j] = mfma16(afr[i], bfr[j], acc[i][j]);
        __builtin_amdgcn_s_setprio(0);
        __builtin_amdgcn_sched_barrier(0);
        __builtin_amdgcn_s_barrier();            // all waves done reading buf t
        __builtin_amdgcn_sched_barrier(0);
    }

    // ---- epilogue ----
    #pragma unroll
    for (int i = 0; i < MI; ++i) {
        const int mf = bm + wr * 128 + i * 16 + ls4 * 4;   // rows mf..mf+3
        #pragma unroll
        for (int j = 0; j < NI; ++j) {
            const int nn = bn + wc * WN + j * 16 + lr;
            const f32x4 a = acc[i][j];
            if constexpr (EPI == 0) {
                float s[4];
                #pragma unroll
                for (int r = 0; r < 4; ++r) s[r] = siluf(a[r] + e0[nn]);
                bf16x4v h;
                #pragma unroll
                for (int r = 0; r < 4; ++r) h[r] = (bf16)s[r];
                if (nn < HIDD)
                    *reinterpret_cast<bf16x4v*>(&Oz[(size_t)nn * ldo + mf]) = h;
                else
                    *reinterpret_cast<bf16x4v*>(&Gz[(size_t)(nn - HIDD) * ldg + mf]) = h;
            } else if constexpr (EPI == 3) {
                const bf16x4v g4 = *reinterpret_cast<const bf16x4v*>(&Gz[(size_t)nn * ldg + mf]);
                #pragma unroll
                for (int r = 0; r < 4; ++r)
                    Oz[(size_t)(mf + r) * ldo + nn] = (bf16)(a[r] * (float)g4[r]);
            } else {
                #pragma unroll
                for (int r = 0; r < 4; ++r)
                    F[(size_t)(mf + r) * ldf + nn] = a[r] + e0[nn];
            }
        }
    }
}

// ---------------- old 2-barrier kernel: kept for qk (EPI1) and sim (EPI2) ----------
template<int EPI, bool SPLIT, int MI, int NI>
__global__ __launch_bounds__(256) void gmm(
    const bf16* __restrict__ Ah, const bf16* __restrict__ Al, int lda, long long sA,
    const bf16* __restrict__ Bh, const bf16* __restrict__ Bl, int ldb, long long sB,
    bf16* __restrict__ O, int ldo, long long sO,
    bf16* __restrict__ O2, bf16* __restrict__ O3, bf16* __restrict__ O4,
    const float* __restrict__ e0, const float* __restrict__ e1, const float* __restrict__ e2,
    int K, float scale) {

    constexpr int TM = MI * 32, TN = NI * 32;
    constexpr int CHA = TM / 64, CHB = TN / 64;
    __shared__ __align__(16) bf16 As[TM * 32];
    __shared__ __align__(16) bf16 Bs[TN * 32];

    const int z = blockIdx.z;
    Ah += (size_t)sA * z;
    if (SPLIT) Al += (size_t)sA * z;
    Bh += (size_t)sB * z;
    if (SPLIT) Bl += (size_t)sB * z;
    if (O) O += (size_t)sO * z;

    const int t = threadIdx.x;
    const int l = t & 63, w = t >> 6;
    const int wr = w >> 1, wc = w & 1;
    const int lr = l & 15, ls = l >> 4;
    const int bm = blockIdx.y * TM, bn = blockIdx.x * TN;

    f32x4 acc[MI][NI] = {};
    const int KT = SPLIT ? 3 * K : K;

    for (int k0 = 0; k0 < KT; k0 += 32) {
        const bf16 *pA, *pB;
        int kin;
        if constexpr (SPLIT) {
            if (k0 < K)          { pA = Ah; pB = Bh; kin = k0; }
            else if (k0 < 2 * K) { pA = Al; pB = Bh; kin = k0 - K; }
            else                 { pA = Ah; pB = Bl; kin = k0 - 2 * K; }
        } else { pA = Ah; pB = Bh; kin = k0; }

        #pragma unroll
        for (int c = 0; c < CHA; ++c) {
            const int idx = c * 256 + w * 64 + l;
            const int row = idx >> 2;
            const int sg = (idx & 3) ^ ((row >> 1) & 3);
            gload16(pA + (size_t)(bm + row) * lda + kin + sg * 8,
                    As + (size_t)(c * 256 + w * 64) * 8);
        }
        #pragma unroll
        for (int c = 0; c < CHB; ++c) {
            const int idx = c * 256 + w * 64 + l;
            const int row = idx >> 2;
            const int sg = (idx & 3) ^ ((row >> 1) & 3);
            gload16(pB + (size_t)(bn + row) * ldb + kin + sg * 8,
                    Bs + (size_t)(c * 256 + w * 64) * 8);
        }
        __syncthreads();

        bf16x8 bfr[NI];
        #pragma unroll
        for (int j = 0; j < NI; ++j) {
            const int row = wc * (NI * 16) + j * 16 + lr;
            const int sl = ls ^ ((row >> 1) & 3);
            bfr[j] = *reinterpret_cast<const bf16x8*>(&Bs[row * 32 + sl * 8]);
        }
        #pragma unroll
        for (int i = 0; i < MI; ++i) {
            const int row = wr * (MI * 16) + i * 16 + lr;
            const int sl = ls ^ ((row >> 1) & 3);
            const bf16x8 af = *reinterpret_cast<const bf16x8*>(&As[row * 32 + sl * 8]);
            #pragma unroll
            for (int j = 0; j < NI; ++j)
                acc[i][j] = mfma16(af, bfr[j], acc[i][j]);
        }
        __syncthreads();
    }

    #pragma unroll
    for (int i = 0; i < MI; ++i) {
        const int mf = bm + wr * (MI * 16) + i * 16 + ls * 4;
        #pragma unroll
        for (int j = 0; j < NI; ++j) {
            const int nn = bn + wc * (NI * 16) + j * 16 + lr;
            const f32x4 a = acc[i][j];
            if constexpr (EPI == 1) {
                #pragma unroll
                for (int r = 0; r < 4; ++r) {
                    const float s = siluf(a[r] + e0[nn]);
                    const float q = s * e1[nn] + e2[nn];
                    const float k = s * e1[QKD + nn] + e2[QKD + nn];
                    bf16 h, lo;
                    splitf(q, h, lo);
                    O[(size_t)(mf + r) * ldo + nn] = h;  O2[(size_t)(mf + r) * ldo + nn] = lo;
                    splitf(k, h, lo);
                    O3[(size_t)(mf + r) * ldo + nn] = h; O4[(size_t)(mf + r) * ldo + nn] = lo;
                }
            } else if constexpr (EPI == 2) {
                #pragma unroll
                for (int r = 0; r < 4; ++r) {
                    const float tv = a[r] * scale;
                    const float p = tv > 0.f ? tv * tv : 0.f;
                    O[(size_t)(mf + r) * ldo + nn] = (bf16)p;
                }
            }
        }
    }
}

extern "C" void kernel_launch(void* const* d_in, const int* in_sizes, int n_in,
                              void* d_out, int out_size, void* d_ws, size_t ws_size,
                              hipStream_t stream) {
    const float* x        = (const float*)d_in[0];
    const float* ln_scale = (const float*)d_in[1];
    const float* ln_bias  = (const float*)d_in[2];
    const float* W_hidden = (const float*)d_in[3];
    const float* b_hidden = (const float*)d_in[4];
    const float* W_qk     = (const float*)d_in[5];
    const float* b_qk     = (const float*)d_in[6];
    const float* os_w     = (const float*)d_in[7];
    const float* os_b     = (const float*)d_in[8];
    const float* W_out    = (const float*)d_in[9];
    const float* b_out    = (const float*)d_in[10];
    float* out = (float*)d_out;

    // ---- weight prep area ----
    char* p = (char*)d_ws;
    bf16* WhTh  = (bf16*)p; p += (size_t)4096 * 1024 * 2;   // [4096][1024]
    bf16* WqkTh = (bf16*)p; p += (size_t)128 * 1024 * 2;    // [128][1024] hi
    bf16* WqkTl = (bf16*)p; p += (size_t)128 * 1024 * 2;    // lo
    bf16* WoTh  = (bf16*)p; p += (size_t)1024 * 2048 * 2;   // [1024][2048]

    wsplitT<<<dim3(4096 / 32, 1024 / 32), 256, 0, stream>>>(W_hidden, 1024, 4096, WhTh, nullptr);
    wsplitT<<<dim3(128 / 32, 1024 / 32), 256, 0, stream>>>(W_qk, 1024, 128, WqkTh, WqkTl);
    wsplitT<<<dim3(1024 / 32, 2048 / 32), 256, 0, stream>>>(W_out, 2048, 1024, WoTh, nullptr);

    const size_t used = (size_t)(p - (char*)d_ws);
    const size_t qkB   = (size_t)4 * 8192 * 128 * 2;
    const size_t vTB   = (size_t)2048 * 8192 * 2;
    const size_t gateB = (size_t)2048 * 8192 * 2;
    const size_t attnB = (size_t)4 * 2048 * 2048 * 2;
    const size_t yB    = (size_t)8192 * 2048 * 2;
    const bool allb = (ws_size >= used + qkB + vTB + gateB + attnB + yB + (1u << 20));

    if (allb) {
        bf16* xh = (bf16*)out;                      // d_out doubles as xn hi/lo
        bf16* xl = xh + (size_t)8192 * 1024;
        bf16* qh   = (bf16*)p; p += (size_t)8192 * 128 * 2;
        bf16* ql   = (bf16*)p; p += (size_t)8192 * 128 * 2;
        bf16* kh   = (bf16*)p; p += (size_t)8192 * 128 * 2;
        bf16* kl   = (bf16*)p; p += (size_t)8192 * 128 * 2;
        bf16* vT   = (bf16*)p; p += vTB;            // [2048][8192]
        bf16* gateT= (bf16*)p; p += gateB;          // [2048][8192]
        bf16* attn = (bf16*)p; p += attnB;          // [4][2048][2048]
        bf16* y    = (bf16*)p; p += yB;             // [8192][2048]

        ln_split<<<8192, 256, 0, stream>>>(x, ln_scale, ln_bias, xh, xl);

        // hid: [8192 x 4096] -> vT + gateT
        gmm2<0, 256><<<dim3(4096 / 256, 8192 / 256), 512, 0, stream>>>(
            xh, 1024, 0, WhTh, 1024, 0,
            vT, 8192, 0, gateT, 8192, 0,
            nullptr, 0, b_hidden, 1024);

        // qk (split): [8192 x 128] -> q,k hi/lo
        gmm<1, true, 2, 2><<<dim3(128 / 64, 8192 / 64), 256, 0, stream>>>(
            xh, xl, 1024, 0, WqkTh, WqkTl, 1024, 0,
            qh, 128, 0, ql, kh, kl,
            b_qk, os_w, os_b, 1024, 0.f);

        // sim (split): per-batch [2048 x 2048]
        gmm<2, true, 4, 4><<<dim3(16, 16, 4), 256, 0, stream>>>(
            qh, ql, 128, (long long)2048 * 128, kh, kl, 128, (long long)2048 * 128,
            attn, 2048, (long long)2048 * 2048, nullptr, nullptr, nullptr,
            nullptr, nullptr, nullptr, 128, 1.0f / SEQ);

        // av: [2048 x 2048] per batch, * gate
        gmm2<3, 256><<<dim3(2048 / 256, 2048 / 256, 4), 512, 0, stream>>>(
            attn, 2048, (long long)2048 * 2048, vT, 8192, 2048,
            y, 2048, (long long)2048 * 2048, gateT, 8192, 2048,
            nullptr, 0, nullptr, 2048);

        // out: [8192 x 1024] fp32 -> d_out
        gmm2<4, 128><<<dim3(1024 / 128, 8192 / 256), 512, 0, stream>>>(
            y, 2048, 0, WoTh, 2048, 0,
            nullptr, 0, 0, nullptr, 0, 0,
            out, 1024, b_out, 2048);
    } else {
        // ---------------- per-batch fallback ----------------
        bf16* xh = (bf16*)p; p += (size_t)8192 * 1024 * 2;
        bf16* xl = (bf16*)p; p += (size_t)8192 * 1024 * 2;
        bf16* qh   = (bf16*)p; p += (size_t)2048 * 128 * 2;
        bf16* ql   = (bf16*)p; p += (size_t)2048 * 128 * 2;
        bf16* kh   = (bf16*)p; p += (size_t)2048 * 128 * 2;
        bf16* kl   = (bf16*)p; p += (size_t)2048 * 128 * 2;
        bf16* vT   = (bf16*)p; p += (size_t)2048 * 2048 * 2;
        bf16* gateT= (bf16*)p; p += (size_t)2048 * 2048 * 2;
        bf16* attn = (bf16*)p; p += (size_t)2048 * 2048 * 2;
        bf16* y    = (bf16*)p; p += (size_t)2048 * 2048 * 2;

        ln_split<<<8192, 256, 0, stream>>>(x, ln_scale, ln_bias, xh, xl);

        for (int b = 0; b < BATCH; ++b) {
            const bf16* xhb = xh + (size_t)b * 2048 * 1024;
            const bf16* xlb = xl + (size_t)b * 2048 * 1024;

            gmm2<0, 256><<<dim3(4096 / 256, 2048 / 256), 512, 0, stream>>>(
                xhb, 1024, 0, WhTh, 1024, 0,
                vT, 2048, 0, gateT, 2048, 0,
                nullptr, 0, b_hidden, 1024);

            gmm<1, true, 2, 2><<<dim3(128 / 64, 2048 / 64), 256, 0, stream>>>(
                xhb, xlb, 1024, 0, WqkTh, WqkTl, 1024, 0,
                qh, 128, 0, ql, kh, kl,
                b_qk, os_w, os_b, 1024, 0.f);

            gmm<2, true, 4, 4><<<dim3(16, 16, 1), 256, 0, stream>>>(
                qh, ql, 128, 0, kh, kl, 128, 0,
                attn, 2048, 0, nullptr, nullptr, nullptr,
                nullptr, nullptr, nullptr, 128, 1.0f / SEQ);

            gmm2<3, 256><<<dim3(2048 / 256, 2048 / 256, 1), 512, 0, stream>>>(
                attn, 2048, 0, vT, 2048, 0,
                y, 2048, 0, gateT, 2048, 0,
                nullptr, 0, nullptr, 2048);

            gmm2<4, 128><<<dim3(1024 / 128, 2048 / 256), 512, 0, stream>>>(
                y, 2048, 0, WoTh, 2048, 0,
                nullptr, 0, 0, nullptr, 0, 0,
                out + (size_t)b * 2048 * 1024, 1024, b_out, 2048);
        }
    }
}

// Round 6
// 303.088 us; speedup vs baseline: 7.9075x; 1.0095x over previous
//
#include <hip/hip_runtime.h>
#include <math.h>

#define DIMX 1024
#define QKD  128
#define HIDD 2048
#define BATCH 4
#define SEQ  2048

typedef __bf16 bf16;
typedef __bf16 bf16x8 __attribute__((ext_vector_type(8)));
typedef __bf16 bf16x4v __attribute__((ext_vector_type(4)));
typedef float f32x4 __attribute__((ext_vector_type(4)));

__device__ __forceinline__ float siluf(float v) { return v / (1.f + expf(-v)); }
__device__ __forceinline__ void splitf(float x, bf16& h, bf16& l) {
    h = (bf16)x;
    l = (bf16)(x - (float)h);
}
__device__ __forceinline__ f32x4 mfma16(bf16x8 a, bf16x8 b, f32x4 c) {
    return __builtin_amdgcn_mfma_f32_16x16x32_bf16(a, b, c, 0, 0, 0);
}

typedef __attribute__((address_space(1))) const void cg_void;
typedef __attribute__((address_space(3))) void lds_void_t;
__device__ __forceinline__ void gload16(const bf16* g, bf16* l) {
    __builtin_amdgcn_global_load_lds((cg_void*)g, (lds_void_t*)l, 16, 0, 0);
}

template<int N> __device__ __forceinline__ void wait_vm() {
    if constexpr (N == 0)  asm volatile("s_waitcnt vmcnt(0)" ::: "memory");
    if constexpr (N == 3)  asm volatile("s_waitcnt vmcnt(3)" ::: "memory");
    if constexpr (N == 4)  asm volatile("s_waitcnt vmcnt(4)" ::: "memory");
    if constexpr (N == 6)  asm volatile("s_waitcnt vmcnt(6)" ::: "memory");
    if constexpr (N == 8)  asm volatile("s_waitcnt vmcnt(8)" ::: "memory");
    if constexpr (N == 9)  asm volatile("s_waitcnt vmcnt(9)" ::: "memory");
    if constexpr (N == 12) asm volatile("s_waitcnt vmcnt(12)" ::: "memory");
}

// -------------------- LayerNorm -> split bf16 hi/lo --------------------
__global__ __launch_bounds__(256) void ln_split(const float* __restrict__ x,
                                                const float* __restrict__ scale,
                                                const float* __restrict__ bias,
                                                bf16* __restrict__ xh,
                                                bf16* __restrict__ xl) {
    const int row = blockIdx.x;
    const float4 v = reinterpret_cast<const float4*>(x + (size_t)row * DIMX)[threadIdx.x];
    float s  = v.x + v.y + v.z + v.w;
    float ss = v.x * v.x + v.y * v.y + v.z * v.z + v.w * v.w;
    #pragma unroll
    for (int off = 32; off; off >>= 1) {
        s  += __shfl_down(s, off);
        ss += __shfl_down(ss, off);
    }
    __shared__ float ls[4], lss[4];
    const int wid = threadIdx.x >> 6, lane = threadIdx.x & 63;
    if (lane == 0) { ls[wid] = s; lss[wid] = ss; }
    __syncthreads();
    if (threadIdx.x == 0) {
        float a = ls[0] + ls[1] + ls[2] + ls[3];
        float b = lss[0] + lss[1] + lss[2] + lss[3];
        float mu  = a / DIMX;
        float var = b / DIMX - mu * mu;
        ls[0]  = mu;
        lss[0] = rsqrtf(var + 1e-5f);
    }
    __syncthreads();
    const float mu = ls[0], rs = lss[0];
    const float4 sc = reinterpret_cast<const float4*>(scale)[threadIdx.x];
    const float4 bi = reinterpret_cast<const float4*>(bias)[threadIdx.x];
    float o[4];
    o[0] = (v.x - mu) * rs * sc.x + bi.x;
    o[1] = (v.y - mu) * rs * sc.y + bi.y;
    o[2] = (v.z - mu) * rs * sc.z + bi.z;
    o[3] = (v.w - mu) * rs * sc.w + bi.w;
    bf16x4v h, l;
    #pragma unroll
    for (int i = 0; i < 4; ++i) { bf16 hh, ll; splitf(o[i], hh, ll); h[i] = hh; l[i] = ll; }
    *reinterpret_cast<bf16x4v*>(xh + (size_t)row * DIMX + threadIdx.x * 4) = h;
    *reinterpret_cast<bf16x4v*>(xl + (size_t)row * DIMX + threadIdx.x * 4) = l;
}

// ------------- transpose + split: W [K][N] fp32 -> T[N][K] bf16 hi(/lo) -------------
__global__ __launch_bounds__(256) void wsplitT(const float* __restrict__ W, int K, int N,
                                               bf16* __restrict__ Th, bf16* __restrict__ Tl) {
    __shared__ float tile[32][33];
    const int bx = blockIdx.x * 32;   // N dir
    const int by = blockIdx.y * 32;   // K dir
    const int tx = threadIdx.x & 31, ty = threadIdx.x >> 5;
    #pragma unroll
    for (int r = 0; r < 32; r += 8)
        tile[ty + r][tx] = W[(size_t)(by + ty + r) * N + bx + tx];
    __syncthreads();
    #pragma unroll
    for (int r = 0; r < 32; r += 8) {
        const float v = tile[tx][ty + r];
        bf16 h, l; splitf(v, h, l);
        Th[(size_t)(bx + ty + r) * K + by + tx] = h;
        if (Tl) Tl[(size_t)(bx + ty + r) * K + by + tx] = l;
    }
}

// =====================================================================
// gmm3: phase-structured MFMA GEMM.  256x256 tile, BK=32, 512 threads
// (8 waves, 2Mx4N), 14-slot half-tile LDS ring (112 KB), derived
// counted vmcnt (8/4/0), 2 setprio MFMA clusters per K-tile with a
// mid-tile barrier (wave role-split).
// A [M][K] (lda), B [N][K] (ldb), fp32 accum.
// EPI 0 (hid): s=silu(acc+e0[n]); n<HIDD -> O[n][m] (vT), else G[n-HIDD][m] (gateT)
// EPI 3 (av):  y = acc * G[n][m] -> O[m][n] bf16
// =====================================================================
template<int EPI>
__global__ __launch_bounds__(512) void gmm3(
    const bf16* __restrict__ A, int lda, long long sA,
    const bf16* __restrict__ B, int ldb, long long sB,
    bf16* __restrict__ O, int ldo, long long sO,
    bf16* __restrict__ G, int ldg, long long sG,
    const float* __restrict__ e0,
    int K) {

    constexpr int BK = 32;
    constexpr int SLOT = 4096;                    // bf16 elems per 8 KB half
    __shared__ __align__(16) bf16 lds[14 * SLOT]; // 112 KB ring

    const int z = blockIdx.z;
    A += (size_t)sA * z;
    B += (size_t)sB * z;
    bf16* Oz = O ? O + (size_t)sO * z : nullptr;
    bf16* Gz = G ? G + (size_t)sG * z : nullptr;

    const int tid = threadIdx.x;
    const int l = tid & 63, w = tid >> 6;
    const int wr = w >> 2, wc = w & 3;            // 2 x 4 wave grid
    const int lr = l & 15, ls4 = l >> 4;
    const int bm = blockIdx.y * 256, bn = blockIdx.x * 256;

    // staging: thread -> (row 0..127, XOR-swizzled k-chunk); LDS dest linear
    const int srow = tid >> 2;
    const int schk = (tid & 3) ^ ((srow >> 1) & 3);
    const bf16* pA0 = A + (size_t)(bm + srow) * lda + schk * 8;
    const bf16* pA1 = A + (size_t)(bm + 128 + srow) * lda + schk * 8;
    const bf16* pB0 = B + (size_t)(bn + srow) * ldb + schk * 8;
    const bf16* pB1 = B + (size_t)(bn + 128 + srow) * ldb + schk * 8;
    bf16* dstw = lds + w * 512;                   // + slot*SLOT

    // fragment reads: matching XOR swizzle ((row>>1)&3 == (lr>>1)&3 here)
    const int koff = (ls4 ^ ((lr >> 1) & 3)) * 8;
    const bf16* rdA = lds + lr * 32 + koff;
    const bf16* rdB = lds + ((wc & 1) * 64 + lr) * 32 + koff;

    const int NT = K / BK;
    f32x4 acc[8][4] = {};

    // prologue: halves g=0..9  (tiles 0,1 complete + A halves of tile 2)
    gload16(pA0, dstw + 0 * SLOT);
    gload16(pA1, dstw + 1 * SLOT);
    gload16(pB0, dstw + 2 * SLOT);
    gload16(pB1, dstw + 3 * SLOT);
    if (1 < NT) {
        gload16(pA0 + BK, dstw + 4 * SLOT);
        gload16(pA1 + BK, dstw + 5 * SLOT);
        gload16(pB0 + BK, dstw + 6 * SLOT);
        gload16(pB1 + BK, dstw + 7 * SLOT);
    }
    if (2 < NT) {
        gload16(pA0 + 2 * BK, dstw + 8 * SLOT);
        gload16(pA1 + 2 * BK, dstw + 9 * SLOT);
    }

    int stSlot = 10;              // slot of B0(u+2) stage; ring advances +4 mod 14
    int saSlot = wr;              // this tile's A-half slot
    int sbSlot = 2 + (wc >> 1);   // this tile's B-half slot

    for (int u = 0; u < NT; ++u) {
        // ---- phase 0: stage B halves of tile u+2, wait tile u, cluster 0 ----
        if (u + 2 < NT) {
            int s1 = stSlot + 1; if (s1 >= 14) s1 -= 14;
            gload16(pB0 + (size_t)(u + 2) * BK, dstw + stSlot * SLOT);
            gload16(pB1 + (size_t)(u + 2) * BK, dstw + s1 * SLOT);
        }
        if (u >= NT - 1)      wait_vm<0>();
        else if (u == NT - 2) wait_vm<4>();
        else                  wait_vm<8>();
        __builtin_amdgcn_s_barrier();            // tile-u halves visible to all
        __builtin_amdgcn_sched_barrier(0);

        const bf16* ab = rdA + saSlot * SLOT;
        const bf16* bb = rdB + sbSlot * SLOT;
        bf16x8 af[4], af2[4], bfr[4];
        #pragma unroll
        for (int j = 0; j < 4; ++j)
            bfr[j] = *reinterpret_cast<const bf16x8*>(&bb[j * 512]);
        #pragma unroll
        for (int i = 0; i < 4; ++i)
            af[i] = *reinterpret_cast<const bf16x8*>(&ab[i * 512]);
        #pragma unroll
        for (int i = 0; i < 4; ++i)
            af2[i] = *reinterpret_cast<const bf16x8*>(&ab[(4 + i) * 512]);
        asm volatile("s_waitcnt lgkmcnt(0)" ::: "memory");
        __builtin_amdgcn_sched_barrier(0);
        __builtin_amdgcn_s_setprio(1);
        #pragma unroll
        for (int i = 0; i < 4; ++i)
            #pragma unroll
            for (int j = 0; j < 4; ++j)
                acc[i][j] = mfma16(af[i], bfr[j], acc[i][j]);
        __builtin_amdgcn_s_setprio(0);
        __builtin_amdgcn_sched_barrier(0);
        __builtin_amdgcn_s_barrier();            // mid-tile phase boundary
        __builtin_amdgcn_sched_barrier(0);

        // ---- phase 1: stage A halves of tile u+3, cluster 1 ----
        if (u + 3 < NT) {
            int s2 = stSlot + 2; if (s2 >= 14) s2 -= 14;
            int s3 = stSlot + 3; if (s3 >= 14) s3 -= 14;
            gload16(pA0 + (size_t)(u + 3) * BK, dstw + s2 * SLOT);
            gload16(pA1 + (size_t)(u + 3) * BK, dstw + s3 * SLOT);
        }
        __builtin_amdgcn_sched_barrier(0);
        __builtin_amdgcn_s_setprio(1);
        #pragma unroll
        for (int i = 0; i < 4; ++i)
            #pragma unroll
            for (int j = 0; j < 4; ++j)
                acc[4 + i][j] = mfma16(af2[i], bfr[j], acc[4 + i][j]);
        __builtin_amdgcn_s_setprio(0);
        __builtin_amdgcn_sched_barrier(0);

        stSlot += 4; if (stSlot >= 14) stSlot -= 14;
        saSlot += 4; if (saSlot >= 14) saSlot -= 14;
        sbSlot += 4; if (sbSlot >= 14) sbSlot -= 14;
    }

    // ---- epilogue ----
    #pragma unroll
    for (int i = 0; i < 8; ++i) {
        const int mf = bm + wr * 128 + i * 16 + ls4 * 4;   // rows mf..mf+3
        #pragma unroll
        for (int j = 0; j < 4; ++j) {
            const int nn = bn + wc * 64 + j * 16 + lr;
            const f32x4 a = acc[i][j];
            if constexpr (EPI == 0) {
                float s[4];
                #pragma unroll
                for (int r = 0; r < 4; ++r) s[r] = siluf(a[r] + e0[nn]);
                bf16x4v h;
                #pragma unroll
                for (int r = 0; r < 4; ++r) h[r] = (bf16)s[r];
                if (nn < HIDD)
                    *reinterpret_cast<bf16x4v*>(&Oz[(size_t)nn * ldo + mf]) = h;
                else
                    *reinterpret_cast<bf16x4v*>(&Gz[(size_t)(nn - HIDD) * ldg + mf]) = h;
            } else {
                const bf16x4v g4 = *reinterpret_cast<const bf16x4v*>(&Gz[(size_t)nn * ldg + mf]);
                #pragma unroll
                for (int r = 0; r < 4; ++r)
                    Oz[(size_t)(mf + r) * ldo + nn] = (bf16)(a[r] * (float)g4[r]);
            }
        }
    }
}

// =====================================================================
// gmm2 (round-5): ring-buffered GEMM, kept for the out projection.
// EPI 4 (out): F[m][n] = acc + e0[n]  fp32
// =====================================================================
template<int EPI, int BN>
__global__ __launch_bounds__(512) void gmm2(
    const bf16* __restrict__ A, int lda, long long sA,
    const bf16* __restrict__ B, int ldb, long long sB,
    bf16* __restrict__ O, int ldo, long long sO,
    bf16* __restrict__ G, int ldg, long long sG,
    float* __restrict__ F, int ldf,
    const float* __restrict__ e0,
    int K) {

    constexpr int BM = 256, BK = 32;
    constexpr int AE = BM * BK;
    constexpr int BE = BN * BK;
    constexpr int CHA = AE / (512 * 8);
    constexpr int CHB = BE / (512 * 8);
    constexpr int L = CHA + CHB;
    constexpr int WN = BN / 4;
    constexpr int MI = 8, NI = WN / 16;

    __shared__ __align__(16) bf16 lds[4 * (AE + BE)];

    const int z = blockIdx.z;
    A += (size_t)sA * z;
    B += (size_t)sB * z;
    bf16* Oz = O ? O + (size_t)sO * z : nullptr;
    bf16* Gz = G ? G + (size_t)sG * z : nullptr;

    const int tid = threadIdx.x;
    const int l = tid & 63, w = tid >> 6;
    const int wr = w >> 2, wc = w & 3;
    const int lr = l & 15, ls4 = l >> 4;
    const int bm = blockIdx.y * BM, bn = blockIdx.x * BN;

    const bf16* aptr[CHA];
    #pragma unroll
    for (int c = 0; c < CHA; ++c) {
        const int flat = c * 512 + tid;
        const int row = flat >> 2;
        const int slot = (flat & 3) ^ ((row >> 1) & 3);
        aptr[c] = A + (size_t)(bm + row) * lda + slot * 8;
    }
    const bf16* bptr[CHB];
    #pragma unroll
    for (int c = 0; c < CHB; ++c) {
        const int flat = c * 512 + tid;
        const int row = flat >> 2;
        const int slot = (flat & 3) ^ ((row >> 1) & 3);
        bptr[c] = B + (size_t)(bn + row) * ldb + slot * 8;
    }

    int aoff[MI], boff[NI];
    #pragma unroll
    for (int i = 0; i < MI; ++i) {
        const int row = wr * 128 + i * 16 + lr;
        aoff[i] = row * BK + (ls4 ^ ((row >> 1) & 3)) * 8;
    }
    #pragma unroll
    for (int j = 0; j < NI; ++j) {
        const int row = wc * WN + j * 16 + lr;
        boff[j] = row * BK + (ls4 ^ ((row >> 1) & 3)) * 8;
    }

    const int NT = K / BK;
    f32x4 acc[MI][NI] = {};

    auto stage = [&](int tile) {
        const int buf = tile & 3;
        bf16* ab = lds + buf * (AE + BE);
        bf16* bb = ab + AE;
        #pragma unroll
        for (int c = 0; c < CHA; ++c)
            gload16(aptr[c] + tile * BK, ab + (c * 512 + w * 64) * 8);
        #pragma unroll
        for (int c = 0; c < CHB; ++c)
            gload16(bptr[c] + tile * BK, bb + (c * 512 + w * 64) * 8);
    };

    stage(0);
    stage(1);
    stage(2);

    for (int t = 0; t < NT; ++t) {
        if (t + 3 < NT) stage(t + 3);
        const int ahead = NT - 1 - t;
        if (ahead >= 3)      wait_vm<3 * L>();
        else if (ahead == 2) wait_vm<2 * L>();
        else if (ahead == 1) wait_vm<L>();
        else                 wait_vm<0>();
        __builtin_amdgcn_s_barrier();
        __builtin_amdgcn_sched_barrier(0);

        const int buf = t & 3;
        const bf16* ab = lds + buf * (AE + BE);
        const bf16* bb = ab + AE;
        bf16x8 bfr[NI], afr[MI];
        #pragma unroll
        for (int j = 0; j < NI; ++j)
            bfr[j] = *reinterpret_cast<const bf16x8*>(&bb[boff[j]]);
        #pragma unroll
        for (int i = 0; i < MI; ++i)
            afr[i] = *reinterpret_cast<const bf16x8*>(&ab[aoff[i]]);
        __builtin_amdgcn_s_setprio(1);
        #pragma unroll
        for (int i = 0; i < MI; ++i)
            #pragma unroll
            for (int j = 0; j < NI; ++j)
                acc[i][j] = mfma16(afr[i], bfr[j], acc[i][j]);
        __builtin_amdgcn_s_setprio(0);
        __builtin_amdgcn_sched_barrier(0);
        __builtin_amdgcn_s_barrier();
        __builtin_amdgcn_sched_barrier(0);
    }

    #pragma unroll
    for (int i = 0; i < MI; ++i) {
        const int mf = bm + wr * 128 + i * 16 + ls4 * 4;
        #pragma unroll
        for (int j = 0; j < NI; ++j) {
            const int nn = bn + wc * WN + j * 16 + lr;
            const f32x4 a = acc[i][j];
            if constexpr (EPI == 0) {
                float s[4];
                #pragma unroll
                for (int r = 0; r < 4; ++r) s[r] = siluf(a[r] + e0[nn]);
                bf16x4v h;
                #pragma unroll
                for (int r = 0; r < 4; ++r) h[r] = (bf16)s[r];
                if (nn < HIDD)
                    *reinterpret_cast<bf16x4v*>(&Oz[(size_t)nn * ldo + mf]) = h;
                else
                    *reinterpret_cast<bf16x4v*>(&Gz[(size_t)(nn - HIDD) * ldg + mf]) = h;
            } else if constexpr (EPI == 3) {
                const bf16x4v g4 = *reinterpret_cast<const bf16x4v*>(&Gz[(size_t)nn * ldg + mf]);
                #pragma unroll
                for (int r = 0; r < 4; ++r)
                    Oz[(size_t)(mf + r) * ldo + nn] = (bf16)(a[r] * (float)g4[r]);
            } else {
                #pragma unroll
                for (int r = 0; r < 4; ++r)
                    F[(size_t)(mf + r) * ldf + nn] = a[r] + e0[nn];
            }
        }
    }
}

// ---------------- round-4 2-barrier kernel: qk (EPI1) and sim (EPI2) ----------
template<int EPI, bool SPLIT, int MI, int NI>
__global__ __launch_bounds__(256) void gmm(
    const bf16* __restrict__ Ah, const bf16* __restrict__ Al, int lda, long long sA,
    const bf16* __restrict__ Bh, const bf16* __restrict__ Bl, int ldb, long long sB,
    bf16* __restrict__ O, int ldo, long long sO,
    bf16* __restrict__ O2, bf16* __restrict__ O3, bf16* __restrict__ O4,
    const float* __restrict__ e0, const float* __restrict__ e1, const float* __restrict__ e2,
    int K, float scale) {

    constexpr int TM = MI * 32, TN = NI * 32;
    constexpr int CHA = TM / 64, CHB = TN / 64;
    __shared__ __align__(16) bf16 As[TM * 32];
    __shared__ __align__(16) bf16 Bs[TN * 32];

    const int z = blockIdx.z;
    Ah += (size_t)sA * z;
    if (SPLIT) Al += (size_t)sA * z;
    Bh += (size_t)sB * z;
    if (SPLIT) Bl += (size_t)sB * z;
    if (O) O += (size_t)sO * z;

    const int t = threadIdx.x;
    const int l = t & 63, w = t >> 6;
    const int wr = w >> 1, wc = w & 1;
    const int lr = l & 15, ls = l >> 4;
    const int bm = blockIdx.y * TM, bn = blockIdx.x * TN;

    f32x4 acc[MI][NI] = {};
    const int KT = SPLIT ? 3 * K : K;

    for (int k0 = 0; k0 < KT; k0 += 32) {
        const bf16 *pA, *pB;
        int kin;
        if constexpr (SPLIT) {
            if (k0 < K)          { pA = Ah; pB = Bh; kin = k0; }
            else if (k0 < 2 * K) { pA = Al; pB = Bh; kin = k0 - K; }
            else                 { pA = Ah; pB = Bl; kin = k0 - 2 * K; }
        } else { pA = Ah; pB = Bh; kin = k0; }

        #pragma unroll
        for (int c = 0; c < CHA; ++c) {
            const int idx = c * 256 + w * 64 + l;
            const int row = idx >> 2;
            const int sg = (idx & 3) ^ ((row >> 1) & 3);
            gload16(pA + (size_t)(bm + row) * lda + kin + sg * 8,
                    As + (size_t)(c * 256 + w * 64) * 8);
        }
        #pragma unroll
        for (int c = 0; c < CHB; ++c) {
            const int idx = c * 256 + w * 64 + l;
            const int row = idx >> 2;
            const int sg = (idx & 3) ^ ((row >> 1) & 3);
            gload16(pB + (size_t)(bn + row) * ldb + kin + sg * 8,
                    Bs + (size_t)(c * 256 + w * 64) * 8);
        }
        __syncthreads();

        bf16x8 bfr[NI];
        #pragma unroll
        for (int j = 0; j < NI; ++j) {
            const int row = wc * (NI * 16) + j * 16 + lr;
            const int sl = ls ^ ((row >> 1) & 3);
            bfr[j] = *reinterpret_cast<const bf16x8*>(&Bs[row * 32 + sl * 8]);
        }
        #pragma unroll
        for (int i = 0; i < MI; ++i) {
            const int row = wr * (MI * 16) + i * 16 + lr;
            const int sl = ls ^ ((row >> 1) & 3);
            const bf16x8 af = *reinterpret_cast<const bf16x8*>(&As[row * 32 + sl * 8]);
            #pragma unroll
            for (int j = 0; j < NI; ++j)
                acc[i][j] = mfma16(af, bfr[j], acc[i][j]);
        }
        __syncthreads();
    }

    #pragma unroll
    for (int i = 0; i < MI; ++i) {
        const int mf = bm + wr * (MI * 16) + i * 16 + ls * 4;
        #pragma unroll
        for (int j = 0; j < NI; ++j) {
            const int nn = bn + wc * (NI * 16) + j * 16 + lr;
            const f32x4 a = acc[i][j];
            if constexpr (EPI == 1) {
                #pragma unroll
                for (int r = 0; r < 4; ++r) {
                    const float s = siluf(a[r] + e0[nn]);
                    const float q = s * e1[nn] + e2[nn];
                    const float k = s * e1[QKD + nn] + e2[QKD + nn];
                    bf16 h, lo;
                    splitf(q, h, lo);
                    O[(size_t)(mf + r) * ldo + nn] = h;  O2[(size_t)(mf + r) * ldo + nn] = lo;
                    splitf(k, h, lo);
                    O3[(size_t)(mf + r) * ldo + nn] = h; O4[(size_t)(mf + r) * ldo + nn] = lo;
                }
            } else if constexpr (EPI == 2) {
                #pragma unroll
                for (int r = 0; r < 4; ++r) {
                    const float tv = a[r] * scale;
                    const float p = tv > 0.f ? tv * tv : 0.f;
                    O[(size_t)(mf + r) * ldo + nn] = (bf16)p;
                }
            }
        }
    }
}

extern "C" void kernel_launch(void* const* d_in, const int* in_sizes, int n_in,
                              void* d_out, int out_size, void* d_ws, size_t ws_size,
                              hipStream_t stream) {
    const float* x        = (const float*)d_in[0];
    const float* ln_scale = (const float*)d_in[1];
    const float* ln_bias  = (const float*)d_in[2];
    const float* W_hidden = (const float*)d_in[3];
    const float* b_hidden = (const float*)d_in[4];
    const float* W_qk     = (const float*)d_in[5];
    const float* b_qk     = (const float*)d_in[6];
    const float* os_w     = (const float*)d_in[7];
    const float* os_b     = (const float*)d_in[8];
    const float* W_out    = (const float*)d_in[9];
    const float* b_out    = (const float*)d_in[10];
    float* out = (float*)d_out;

    // ---- weight prep area ----
    char* p = (char*)d_ws;
    bf16* WhTh  = (bf16*)p; p += (size_t)4096 * 1024 * 2;   // [4096][1024]
    bf16* WqkTh = (bf16*)p; p += (size_t)128 * 1024 * 2;    // [128][1024] hi
    bf16* WqkTl = (bf16*)p; p += (size_t)128 * 1024 * 2;    // lo
    bf16* WoTh  = (bf16*)p; p += (size_t)1024 * 2048 * 2;   // [1024][2048]

    wsplitT<<<dim3(4096 / 32, 1024 / 32), 256, 0, stream>>>(W_hidden, 1024, 4096, WhTh, nullptr);
    wsplitT<<<dim3(128 / 32, 1024 / 32), 256, 0, stream>>>(W_qk, 1024, 128, WqkTh, WqkTl);
    wsplitT<<<dim3(1024 / 32, 2048 / 32), 256, 0, stream>>>(W_out, 2048, 1024, WoTh, nullptr);

    const size_t used = (size_t)(p - (char*)d_ws);
    const size_t qkB   = (size_t)4 * 8192 * 128 * 2;
    const size_t vTB   = (size_t)2048 * 8192 * 2;
    const size_t gateB = (size_t)2048 * 8192 * 2;
    const size_t attnB = (size_t)4 * 2048 * 2048 * 2;
    const size_t yB    = (size_t)8192 * 2048 * 2;
    const bool allb = (ws_size >= used + qkB + vTB + gateB + attnB + yB + (1u << 20));

    if (allb) {
        bf16* xh = (bf16*)out;                      // d_out doubles as xn hi/lo
        bf16* xl = xh + (size_t)8192 * 1024;
        bf16* qh   = (bf16*)p; p += (size_t)8192 * 128 * 2;
        bf16* ql   = (bf16*)p; p += (size_t)8192 * 128 * 2;
        bf16* kh   = (bf16*)p; p += (size_t)8192 * 128 * 2;
        bf16* kl   = (bf16*)p; p += (size_t)8192 * 128 * 2;
        bf16* vT   = (bf16*)p; p += vTB;            // [2048][8192]
        bf16* gateT= (bf16*)p; p += gateB;          // [2048][8192]
        bf16* attn = (bf16*)p; p += attnB;          // [4][2048][2048]
        bf16* y    = (bf16*)p; p += yB;             // [8192][2048]

        ln_split<<<8192, 256, 0, stream>>>(x, ln_scale, ln_bias, xh, xl);

        // hid: [8192 x 4096] -> vT + gateT
        gmm3<0><<<dim3(4096 / 256, 8192 / 256), 512, 0, stream>>>(
            xh, 1024, 0, WhTh, 1024, 0,
            vT, 8192, 0, gateT, 8192, 0,
            b_hidden, 1024);

        // qk (split): [8192 x 128] -> q,k hi/lo
        gmm<1, true, 2, 2><<<dim3(128 / 64, 8192 / 64), 256, 0, stream>>>(
            xh, xl, 1024, 0, WqkTh, WqkTl, 1024, 0,
            qh, 128, 0, ql, kh, kl,
            b_qk, os_w, os_b, 1024, 0.f);

        // sim (split): per-batch [2048 x 2048]
        gmm<2, true, 4, 4><<<dim3(16, 16, 4), 256, 0, stream>>>(
            qh, ql, 128, (long long)2048 * 128, kh, kl, 128, (long long)2048 * 128,
            attn, 2048, (long long)2048 * 2048, nullptr, nullptr, nullptr,
            nullptr, nullptr, nullptr, 128, 1.0f / SEQ);

        // av: [2048 x 2048] per batch, * gate
        gmm3<3><<<dim3(2048 / 256, 2048 / 256, 4), 512, 0, stream>>>(
            attn, 2048, (long long)2048 * 2048, vT, 8192, 2048,
            y, 2048, (long long)2048 * 2048, gateT, 8192, 2048,
            nullptr, 2048);

        // out: [8192 x 1024] fp32 -> d_out
        gmm2<4, 128><<<dim3(1024 / 128, 8192 / 256), 512, 0, stream>>>(
            y, 2048, 0, WoTh, 2048, 0,
            nullptr, 0, 0, nullptr, 0, 0,
            out, 1024, b_out, 2048);
    } else {
        // ---------------- per-batch fallback ----------------
        bf16* xh = (bf16*)p; p += (size_t)8192 * 1024 * 2;
        bf16* xl = (bf16*)p; p += (size_t)8192 * 1024 * 2;
        bf16* qh   = (bf16*)p; p += (size_t)2048 * 128 * 2;
        bf16* ql   = (bf16*)p; p += (size_t)2048 * 128 * 2;
        bf16* kh   = (bf16*)p; p += (size_t)2048 * 128 * 2;
        bf16* kl   = (bf16*)p; p += (size_t)2048 * 128 * 2;
        bf16* vT   = (bf16*)p; p += (size_t)2048 * 2048 * 2;
        bf16* gateT= (bf16*)p; p += (size_t)2048 * 2048 * 2;
        bf16* attn = (bf16*)p; p += (size_t)2048 * 2048 * 2;
        bf16* y    = (bf16*)p; p += (size_t)2048 * 2048 * 2;

        ln_split<<<8192, 256, 0, stream>>>(x, ln_scale, ln_bias, xh, xl);

        for (int b = 0; b < BATCH; ++b) {
            const bf16* xhb = xh + (size_t)b * 2048 * 1024;
            const bf16* xlb = xl + (size_t)b * 2048 * 1024;

            gmm3<0><<<dim3(4096 / 256, 2048 / 256), 512, 0, stream>>>(
                xhb, 1024, 0, WhTh, 1024, 0,
                vT, 2048, 0, gateT, 2048, 0,
                b_hidden, 1024);

            gmm<1, true, 2, 2><<<dim3(128 / 64, 2048 / 64), 256, 0, stream>>>(
                xhb, xlb, 1024, 0, WqkTh, WqkTl, 1024, 0,
                qh, 128, 0, ql, kh, kl,
                b_qk, os_w, os_b, 1024, 0.f);

            gmm<2, true, 4, 4><<<dim3(16, 16, 1), 256, 0, stream>>>(
                qh, ql, 128, 0, kh, kl, 128, 0,
                attn, 2048, 0, nullptr, nullptr, nullptr,
                nullptr, nullptr, nullptr, 128, 1.0f / SEQ);

            gmm3<3><<<dim3(2048 / 256, 2048 / 256, 1), 512, 0, stream>>>(
                attn, 2048, 0, vT, 2048, 0,
                y, 2048, 0, gateT, 2048, 0,
                nullptr, 2048);

            gmm2<4, 128><<<dim3(1024 / 128, 2048 / 256), 512, 0, stream>>>(
                y, 2048, 0, WoTh, 2048, 0,
                nullptr, 0, 0, nullptr, 0, 0,
                out + (size_t)b * 2048 * 1024, 1024, b_out, 2048);
        }
    }
}

// Round 9
// 293.653 us; speedup vs baseline: 8.1616x; 1.0321x over previous
//
#include <hip/hip_runtime.h>
#include <math.h>

#define DIMX 1024
#define QKD  128
#define HIDD 2048
#define BATCH 4
#define SEQ  2048

typedef __bf16 bf16;
typedef __bf16 bf16x8 __attribute__((ext_vector_type(8)));
typedef __bf16 bf16x4v __attribute__((ext_vector_type(4)));
typedef float f32x4 __attribute__((ext_vector_type(4)));

__device__ __forceinline__ float siluf(float v) { return v / (1.f + expf(-v)); }
__device__ __forceinline__ void splitf(float x, bf16& h, bf16& l) {
    h = (bf16)x;
    l = (bf16)(x - (float)h);
}
__device__ __forceinline__ f32x4 mfma16(bf16x8 a, bf16x8 b, f32x4 c) {
    return __builtin_amdgcn_mfma_f32_16x16x32_bf16(a, b, c, 0, 0, 0);
}

typedef __attribute__((address_space(1))) const void cg_void;
typedef __attribute__((address_space(3))) void lds_void_t;
__device__ __forceinline__ void gload16(const bf16* g, bf16* l) {
    __builtin_amdgcn_global_load_lds((cg_void*)g, (lds_void_t*)l, 16, 0, 0);
}

template<int N> __device__ __forceinline__ void wait_vm() {
    if constexpr (N == 0)  asm volatile("s_waitcnt vmcnt(0)" ::: "memory");
    if constexpr (N == 3)  asm volatile("s_waitcnt vmcnt(3)" ::: "memory");
    if constexpr (N == 4)  asm volatile("s_waitcnt vmcnt(4)" ::: "memory");
    if constexpr (N == 6)  asm volatile("s_waitcnt vmcnt(6)" ::: "memory");
    if constexpr (N == 8)  asm volatile("s_waitcnt vmcnt(8)" ::: "memory");
}

#define SB0 __builtin_amdgcn_sched_barrier(0)

// -------------------- LayerNorm -> split bf16 hi/lo --------------------
__global__ __launch_bounds__(256) void ln_split(const float* __restrict__ x,
                                                const float* __restrict__ scale,
                                                const float* __restrict__ bias,
                                                bf16* __restrict__ xh,
                                                bf16* __restrict__ xl) {
    const int row = blockIdx.x;
    const float4 v = reinterpret_cast<const float4*>(x + (size_t)row * DIMX)[threadIdx.x];
    float s  = v.x + v.y + v.z + v.w;
    float ss = v.x * v.x + v.y * v.y + v.z * v.z + v.w * v.w;
    #pragma unroll
    for (int off = 32; off; off >>= 1) {
        s  += __shfl_down(s, off);
        ss += __shfl_down(ss, off);
    }
    __shared__ float ls[4], lss[4];
    const int wid = threadIdx.x >> 6, lane = threadIdx.x & 63;
    if (lane == 0) { ls[wid] = s; lss[wid] = ss; }
    __syncthreads();
    if (threadIdx.x == 0) {
        float a = ls[0] + ls[1] + ls[2] + ls[3];
        float b = lss[0] + lss[1] + lss[2] + lss[3];
        float mu  = a / DIMX;
        float var = b / DIMX - mu * mu;
        ls[0]  = mu;
        lss[0] = rsqrtf(var + 1e-5f);
    }
    __syncthreads();
    const float mu = ls[0], rs = lss[0];
    const float4 sc = reinterpret_cast<const float4*>(scale)[threadIdx.x];
    const float4 bi = reinterpret_cast<const float4*>(bias)[threadIdx.x];
    float o[4];
    o[0] = (v.x - mu) * rs * sc.x + bi.x;
    o[1] = (v.y - mu) * rs * sc.y + bi.y;
    o[2] = (v.z - mu) * rs * sc.z + bi.z;
    o[3] = (v.w - mu) * rs * sc.w + bi.w;
    bf16x4v h, l;
    #pragma unroll
    for (int i = 0; i < 4; ++i) { bf16 hh, ll; splitf(o[i], hh, ll); h[i] = hh; l[i] = ll; }
    *reinterpret_cast<bf16x4v*>(xh + (size_t)row * DIMX + threadIdx.x * 4) = h;
    *reinterpret_cast<bf16x4v*>(xl + (size_t)row * DIMX + threadIdx.x * 4) = l;
}

// ------------- transpose + split: W [K][N] fp32 -> T[N][K] bf16 hi(/lo) -------------
__global__ __launch_bounds__(256) void wsplitT(const float* __restrict__ W, int K, int N,
                                               bf16* __restrict__ Th, bf16* __restrict__ Tl) {
    __shared__ float tile[32][33];
    const int bx = blockIdx.x * 32;   // N dir
    const int by = blockIdx.y * 32;   // K dir
    const int tx = threadIdx.x & 31, ty = threadIdx.x >> 5;
    #pragma unroll
    for (int r = 0; r < 32; r += 8)
        tile[ty + r][tx] = W[(size_t)(by + ty + r) * N + bx + tx];
    __syncthreads();
    #pragma unroll
    for (int r = 0; r < 32; r += 8) {
        const float v = tile[tx][ty + r];
        bf16 h, l; splitf(v, h, l);
        Th[(size_t)(bx + ty + r) * K + by + tx] = h;
        if (Tl) Tl[(size_t)(bx + ty + r) * K + by + tx] = l;
    }
}

// =====================================================================
// gmm2: ring-buffered MFMA GEMM (round-5 proven), single-barrier loop.
// BM=256, BK=32, 512 threads (8 waves 2Mx4N), 4-deep LDS ring.
// Loop: [wait_vm(2L); barrier; ds_read(t); lgkm; stage(t+3); MFMA(t)].
// Safety: stage(t+3) overwrites buf[(t-1)&3]; every wave's iter-(t-1)
// reads completed before it arrived at iter-t's barrier (lgkm precedes
// arrival), and the stage is issued only after passing that barrier.
// RAW: at iter-t top, last 2 stages (t+1,t+2) may be outstanding ->
// wait_vm(2L) retires tile t.  Tail: L at t=NT-2, 0 at t=NT-1.
// EPI 0 (hid): s=silu(acc+e0[n]); n<HIDD -> O[n][m] (vT) else G[n-HIDD][m]
// EPI 3 (av):  y = acc * G[n][m] -> O[m][n] bf16
// EPI 4 (out): F[m][n] = acc + e0[n]  fp32
// =====================================================================
template<int EPI, int BN>
__global__ __launch_bounds__(512) void gmm2(
    const bf16* __restrict__ A, int lda, long long sA,
    const bf16* __restrict__ B, int ldb, long long sB,
    bf16* __restrict__ O, int ldo, long long sO,
    bf16* __restrict__ G, int ldg, long long sG,
    float* __restrict__ F, int ldf,
    const float* __restrict__ e0,
    int K) {

    constexpr int BM = 256, BK = 32;
    constexpr int AE = BM * BK;
    constexpr int BE = BN * BK;
    constexpr int CHA = AE / (512 * 8);
    constexpr int CHB = BE / (512 * 8);
    constexpr int L = CHA + CHB;
    constexpr int WN = BN / 4;
    constexpr int MI = 8, NI = WN / 16;

    __shared__ __align__(16) bf16 lds[4 * (AE + BE)];

    const int z = blockIdx.z;
    A += (size_t)sA * z;
    B += (size_t)sB * z;
    bf16* Oz = O ? O + (size_t)sO * z : nullptr;
    bf16* Gz = G ? G + (size_t)sG * z : nullptr;

    const int tid = threadIdx.x;
    const int l = tid & 63, w = tid >> 6;
    const int wr = w >> 2, wc = w & 3;
    const int lr = l & 15, ls4 = l >> 4;
    const int bm = blockIdx.y * BM, bn = blockIdx.x * BN;

    const bf16* aptr[CHA];
    #pragma unroll
    for (int c = 0; c < CHA; ++c) {
        const int flat = c * 512 + tid;
        const int row = flat >> 2;
        const int slot = (flat & 3) ^ ((row >> 1) & 3);
        aptr[c] = A + (size_t)(bm + row) * lda + slot * 8;
    }
    const bf16* bptr[CHB];
    #pragma unroll
    for (int c = 0; c < CHB; ++c) {
        const int flat = c * 512 + tid;
        const int row = flat >> 2;
        const int slot = (flat & 3) ^ ((row >> 1) & 3);
        bptr[c] = B + (size_t)(bn + row) * ldb + slot * 8;
    }

    int aoff[MI], boff[NI];
    #pragma unroll
    for (int i = 0; i < MI; ++i) {
        const int row = wr * 128 + i * 16 + lr;
        aoff[i] = row * BK + (ls4 ^ ((row >> 1) & 3)) * 8;
    }
    #pragma unroll
    for (int j = 0; j < NI; ++j) {
        const int row = wc * WN + j * 16 + lr;
        boff[j] = row * BK + (ls4 ^ ((row >> 1) & 3)) * 8;
    }

    const int NT = K / BK;
    f32x4 acc[MI][NI] = {};

    auto stage = [&](int tile) {
        const int buf = tile & 3;
        bf16* ab = lds + buf * (AE + BE);
        bf16* bb = ab + AE;
        #pragma unroll
        for (int c = 0; c < CHA; ++c)
            gload16(aptr[c] + tile * BK, ab + (c * 512 + w * 64) * 8);
        #pragma unroll
        for (int c = 0; c < CHB; ++c)
            gload16(bptr[c] + tile * BK, bb + (c * 512 + w * 64) * 8);
    };

    stage(0); SB0;
    stage(1); SB0;
    stage(2); SB0;

    for (int t = 0; t < NT; ++t) {
        const int ahead = NT - 1 - t;
        if (ahead >= 2)      wait_vm<2 * L>();   // tiles t+1,t+2 may be in flight
        else if (ahead == 1) wait_vm<L>();
        else                 wait_vm<0>();
        __builtin_amdgcn_s_barrier();            // all waves' tile-t landed
        SB0;

        const int buf = t & 3;
        const bf16* ab = lds + buf * (AE + BE);
        const bf16* bb = ab + AE;
        bf16x8 bfr[NI], afr[MI];
        #pragma unroll
        for (int j = 0; j < NI; ++j)
            bfr[j] = *reinterpret_cast<const bf16x8*>(&bb[boff[j]]);
        #pragma unroll
        for (int i = 0; i < MI; ++i)
            afr[i] = *reinterpret_cast<const bf16x8*>(&ab[aoff[i]]);
        asm volatile("s_waitcnt lgkmcnt(0)" ::: "memory");
        SB0;
        if (t + 3 < NT) { stage(t + 3); }        // overwrites buf[(t-1)&3]: safe
        SB0;
        __builtin_amdgcn_s_setprio(1);
        #pragma unroll
        for (int i = 0; i < MI; ++i)
            #pragma unroll
            for (int j = 0; j < NI; ++j)
                acc[i][j] = mfma16(afr[i], bfr[j], acc[i][j]);
        __builtin_amdgcn_s_setprio(0);
        SB0;
    }

    #pragma unroll
    for (int i = 0; i < MI; ++i) {
        const int mf = bm + wr * 128 + i * 16 + ls4 * 4;
        #pragma unroll
        for (int j = 0; j < NI; ++j) {
            const int nn = bn + wc * WN + j * 16 + lr;
            const f32x4 a = acc[i][j];
            if constexpr (EPI == 0) {
                float s[4];
                #pragma unroll
                for (int r = 0; r < 4; ++r) s[r] = siluf(a[r] + e0[nn]);
                bf16x4v h;
                #pragma unroll
                for (int r = 0; r < 4; ++r) h[r] = (bf16)s[r];
                if (nn < HIDD)
                    *reinterpret_cast<bf16x4v*>(&Oz[(size_t)nn * ldo + mf]) = h;
                else
                    *reinterpret_cast<bf16x4v*>(&Gz[(size_t)(nn - HIDD) * ldg + mf]) = h;
            } else if constexpr (EPI == 3) {
                const bf16x4v g4 = *reinterpret_cast<const bf16x4v*>(&Gz[(size_t)nn * ldg + mf]);
                #pragma unroll
                for (int r = 0; r < 4; ++r)
                    Oz[(size_t)(mf + r) * ldo + nn] = (bf16)(a[r] * (float)g4[r]);
            } else {
                #pragma unroll
                for (int r = 0; r < 4; ++r)
                    F[(size_t)(mf + r) * ldf + nn] = a[r] + e0[nn];
            }
        }
    }
}

// ---------------- round-4 2-barrier kernel: qk (EPI1) and sim (EPI2) ----------
template<int EPI, bool SPLIT, int MI, int NI>
__global__ __launch_bounds__(256) void gmm(
    const bf16* __restrict__ Ah, const bf16* __restrict__ Al, int lda, long long sA,
    const bf16* __restrict__ Bh, const bf16* __restrict__ Bl, int ldb, long long sB,
    bf16* __restrict__ O, int ldo, long long sO,
    bf16* __restrict__ O2, bf16* __restrict__ O3, bf16* __restrict__ O4,
    const float* __restrict__ e0, const float* __restrict__ e1, const float* __restrict__ e2,
    int K, float scale) {

    constexpr int TM = MI * 32, TN = NI * 32;
    constexpr int CHA = TM / 64, CHB = TN / 64;
    __shared__ __align__(16) bf16 As[TM * 32];
    __shared__ __align__(16) bf16 Bs[TN * 32];

    const int z = blockIdx.z;
    Ah += (size_t)sA * z;
    if (SPLIT) Al += (size_t)sA * z;
    Bh += (size_t)sB * z;
    if (SPLIT) Bl += (size_t)sB * z;
    if (O) O += (size_t)sO * z;

    const int t = threadIdx.x;
    const int l = t & 63, w = t >> 6;
    const int wr = w >> 1, wc = w & 1;
    const int lr = l & 15, ls = l >> 4;
    const int bm = blockIdx.y * TM, bn = blockIdx.x * TN;

    f32x4 acc[MI][NI] = {};
    const int KT = SPLIT ? 3 * K : K;

    for (int k0 = 0; k0 < KT; k0 += 32) {
        const bf16 *pA, *pB;
        int kin;
        if constexpr (SPLIT) {
            if (k0 < K)          { pA = Ah; pB = Bh; kin = k0; }
            else if (k0 < 2 * K) { pA = Al; pB = Bh; kin = k0 - K; }
            else                 { pA = Ah; pB = Bl; kin = k0 - 2 * K; }
        } else { pA = Ah; pB = Bh; kin = k0; }

        #pragma unroll
        for (int c = 0; c < CHA; ++c) {
            const int idx = c * 256 + w * 64 + l;
            const int row = idx >> 2;
            const int sg = (idx & 3) ^ ((row >> 1) & 3);
            gload16(pA + (size_t)(bm + row) * lda + kin + sg * 8,
                    As + (size_t)(c * 256 + w * 64) * 8);
        }
        #pragma unroll
        for (int c = 0; c < CHB; ++c) {
            const int idx = c * 256 + w * 64 + l;
            const int row = idx >> 2;
            const int sg = (idx & 3) ^ ((row >> 1) & 3);
            gload16(pB + (size_t)(bn + row) * ldb + kin + sg * 8,
                    Bs + (size_t)(c * 256 + w * 64) * 8);
        }
        __syncthreads();

        bf16x8 bfr[NI];
        #pragma unroll
        for (int j = 0; j < NI; ++j) {
            const int row = wc * (NI * 16) + j * 16 + lr;
            const int sl = ls ^ ((row >> 1) & 3);
            bfr[j] = *reinterpret_cast<const bf16x8*>(&Bs[row * 32 + sl * 8]);
        }
        #pragma unroll
        for (int i = 0; i < MI; ++i) {
            const int row = wr * (MI * 16) + i * 16 + lr;
            const int sl = ls ^ ((row >> 1) & 3);
            const bf16x8 af = *reinterpret_cast<const bf16x8*>(&As[row * 32 + sl * 8]);
            #pragma unroll
            for (int j = 0; j < NI; ++j)
                acc[i][j] = mfma16(af, bfr[j], acc[i][j]);
        }
        __syncthreads();
    }

    #pragma unroll
    for (int i = 0; i < MI; ++i) {
        const int mf = bm + wr * (MI * 16) + i * 16 + ls * 4;
        #pragma unroll
        for (int j = 0; j < NI; ++j) {
            const int nn = bn + wc * (NI * 16) + j * 16 + lr;
            const f32x4 a = acc[i][j];
            if constexpr (EPI == 1) {
                #pragma unroll
                for (int r = 0; r < 4; ++r) {
                    const float s = siluf(a[r] + e0[nn]);
                    const float q = s * e1[nn] + e2[nn];
                    const float k = s * e1[QKD + nn] + e2[QKD + nn];
                    bf16 h, lo;
                    splitf(q, h, lo);
                    O[(size_t)(mf + r) * ldo + nn] = h;  O2[(size_t)(mf + r) * ldo + nn] = lo;
                    splitf(k, h, lo);
                    O3[(size_t)(mf + r) * ldo + nn] = h; O4[(size_t)(mf + r) * ldo + nn] = lo;
                }
            } else if constexpr (EPI == 2) {
                #pragma unroll
                for (int r = 0; r < 4; ++r) {
                    const float tv = a[r] * scale;
                    const float p = tv > 0.f ? tv * tv : 0.f;
                    O[(size_t)(mf + r) * ldo + nn] = (bf16)p;
                }
            }
        }
    }
}

extern "C" void kernel_launch(void* const* d_in, const int* in_sizes, int n_in,
                              void* d_out, int out_size, void* d_ws, size_t ws_size,
                              hipStream_t stream) {
    const float* x        = (const float*)d_in[0];
    const float* ln_scale = (const float*)d_in[1];
    const float* ln_bias  = (const float*)d_in[2];
    const float* W_hidden = (const float*)d_in[3];
    const float* b_hidden = (const float*)d_in[4];
    const float* W_qk     = (const float*)d_in[5];
    const float* b_qk     = (const float*)d_in[6];
    const float* os_w     = (const float*)d_in[7];
    const float* os_b     = (const float*)d_in[8];
    const float* W_out    = (const float*)d_in[9];
    const float* b_out    = (const float*)d_in[10];
    float* out = (float*)d_out;

    // ---- weight prep area ----
    char* p = (char*)d_ws;
    bf16* WhTh  = (bf16*)p; p += (size_t)4096 * 1024 * 2;   // [4096][1024]
    bf16* WqkTh = (bf16*)p; p += (size_t)128 * 1024 * 2;    // [128][1024] hi
    bf16* WqkTl = (bf16*)p; p += (size_t)128 * 1024 * 2;    // lo
    bf16* WoTh  = (bf16*)p; p += (size_t)1024 * 2048 * 2;   // [1024][2048]

    wsplitT<<<dim3(4096 / 32, 1024 / 32), 256, 0, stream>>>(W_hidden, 1024, 4096, WhTh, nullptr);
    wsplitT<<<dim3(128 / 32, 1024 / 32), 256, 0, stream>>>(W_qk, 1024, 128, WqkTh, WqkTl);
    wsplitT<<<dim3(1024 / 32, 2048 / 32), 256, 0, stream>>>(W_out, 2048, 1024, WoTh, nullptr);

    const size_t used = (size_t)(p - (char*)d_ws);
    const size_t qkB   = (size_t)4 * 8192 * 128 * 2;
    const size_t vTB   = (size_t)2048 * 8192 * 2;
    const size_t gateB = (size_t)2048 * 8192 * 2;
    const size_t attnB = (size_t)4 * 2048 * 2048 * 2;
    const size_t yB    = (size_t)8192 * 2048 * 2;
    const bool allb = (ws_size >= used + qkB + vTB + gateB + attnB + yB + (1u << 20));

    if (allb) {
        bf16* xh = (bf16*)out;                      // d_out doubles as xn hi/lo
        bf16* xl = xh + (size_t)8192 * 1024;
        bf16* qh   = (bf16*)p; p += (size_t)8192 * 128 * 2;
        bf16* ql   = (bf16*)p; p += (size_t)8192 * 128 * 2;
        bf16* kh   = (bf16*)p; p += (size_t)8192 * 128 * 2;
        bf16* kl   = (bf16*)p; p += (size_t)8192 * 128 * 2;
        bf16* vT   = (bf16*)p; p += vTB;            // [2048][8192]
        bf16* gateT= (bf16*)p; p += gateB;          // [2048][8192]
        bf16* attn = (bf16*)p; p += attnB;          // [4][2048][2048]
        bf16* y    = (bf16*)p; p += yB;             // [8192][2048]

        ln_split<<<8192, 256, 0, stream>>>(x, ln_scale, ln_bias, xh, xl);

        // hid: [8192 x 4096] -> vT + gateT
        gmm2<0, 256><<<dim3(4096 / 256, 8192 / 256), 512, 0, stream>>>(
            xh, 1024, 0, WhTh, 1024, 0,
            vT, 8192, 0, gateT, 8192, 0,
            nullptr, 0, b_hidden, 1024);

        // qk (split): [8192 x 128] -> q,k hi/lo
        gmm<1, true, 2, 2><<<dim3(128 / 64, 8192 / 64), 256, 0, stream>>>(
            xh, xl, 1024, 0, WqkTh, WqkTl, 1024, 0,
            qh, 128, 0, ql, kh, kl,
            b_qk, os_w, os_b, 1024, 0.f);

        // sim (split): per-batch [2048 x 2048]
        gmm<2, true, 4, 4><<<dim3(16, 16, 4), 256, 0, stream>>>(
            qh, ql, 128, (long long)2048 * 128, kh, kl, 128, (long long)2048 * 128,
            attn, 2048, (long long)2048 * 2048, nullptr, nullptr, nullptr,
            nullptr, nullptr, nullptr, 128, 1.0f / SEQ);

        // av: [2048 x 2048] per batch, * gate
        gmm2<3, 256><<<dim3(2048 / 256, 2048 / 256, 4), 512, 0, stream>>>(
            attn, 2048, (long long)2048 * 2048, vT, 8192, 2048,
            y, 2048, (long long)2048 * 2048, gateT, 8192, 2048,
            nullptr, 0, nullptr, 2048);

        // out: [8192 x 1024] fp32 -> d_out
        gmm2<4, 128><<<dim3(1024 / 128, 8192 / 256), 512, 0, stream>>>(
            y, 2048, 0, WoTh, 2048, 0,
            nullptr, 0, 0, nullptr, 0, 0,
            out, 1024, b_out, 2048);
    } else {
        // ---------------- per-batch fallback ----------------
        bf16* xh = (bf16*)p; p += (size_t)8192 * 1024 * 2;
        bf16* xl = (bf16*)p; p += (size_t)8192 * 1024 * 2;
        bf16* qh   = (bf16*)p; p += (size_t)2048 * 128 * 2;
        bf16* ql   = (bf16*)p; p += (size_t)2048 * 128 * 2;
        bf16* kh   = (bf16*)p; p += (size_t)2048 * 128 * 2;
        bf16* kl   = (bf16*)p; p += (size_t)2048 * 128 * 2;
        bf16* vT   = (bf16*)p; p += (size_t)2048 * 2048 * 2;
        bf16* gateT= (bf16*)p; p += (size_t)2048 * 2048 * 2;
        bf16* attn = (bf16*)p; p += (size_t)2048 * 2048 * 2;
        bf16* y    = (bf16*)p; p += (size_t)2048 * 2048 * 2;

        ln_split<<<8192, 256, 0, stream>>>(x, ln_scale, ln_bias, xh, xl);

        for (int b = 0; b < BATCH; ++b) {
            const bf16* xhb = xh + (size_t)b * 2048 * 1024;
            const bf16* xlb = xl + (size_t)b * 2048 * 1024;

            gmm2<0, 256><<<dim3(4096 / 256, 2048 / 256), 512, 0, stream>>>(
                xhb, 1024, 0, WhTh, 1024, 0,
                vT, 2048, 0, gateT, 2048, 0,
                nullptr, 0, b_hidden, 1024);

            gmm<1, true, 2, 2><<<dim3(128 / 64, 2048 / 64), 256, 0, stream>>>(
                xhb, xlb, 1024, 0, WqkTh, WqkTl, 1024, 0,
                qh, 128, 0, ql, kh, kl,
                b_qk, os_w, os_b, 1024, 0.f);

            gmm<2, true, 4, 4><<<dim3(16, 16, 1), 256, 0, stream>>>(
                qh, ql, 128, 0, kh, kl, 128, 0,
                attn, 2048, 0, nullptr, nullptr, nullptr,
                nullptr, nullptr, nullptr, 128, 1.0f / SEQ);

            gmm2<3, 256><<<dim3(2048 / 256, 2048 / 256, 1), 512, 0, stream>>>(
                attn, 2048, 0, vT, 2048, 0,
                y, 2048, 0, gateT, 2048, 0,
                nullptr, 0, nullptr, 2048);

            gmm2<4, 128><<<dim3(1024 / 128, 2048 / 256), 512, 0, stream>>>(
                y, 2048, 0, WoTh, 2048, 0,
                nullptr, 0, 0, nullptr, 0, 0,
                out + (size_t)b * 2048 * 1024, 1024, b_out, 2048);
        }
    }
}